// Round 6
// baseline (109.149 us; speedup 1.0000x reference)
//
#include <hip/hip_runtime.h>

#define BATCH 4
#define LQ    10000
#define DM    256
#define NH    8
#define NP    4
#define HWD   100
#define LIN   10000
#define PW    103              // padded map width/height (1-px border + right/bottom slack)
#define PP    (PW * PW)        // padded pixels per head-map

typedef unsigned short ushort_t;
typedef __attribute__((ext_vector_type(8))) short bf16x8;
typedef __attribute__((ext_vector_type(8))) unsigned short u16x8;
typedef __attribute__((ext_vector_type(4))) float f32x4;

__device__ __forceinline__ unsigned short f2bf(float f) {
    unsigned int u = __float_as_uint(f);
    u += 0x7FFFu + ((u >> 16) & 1u);          // round-to-nearest-even
    return (unsigned short)(u >> 16);
}

// ---------------------------------------------------------------------------
// Prep: weight transposes (bf16) + combined proj weight + value border zero.
// grid (256,4) x 256 threads.
// ---------------------------------------------------------------------------
__global__ __launch_bounds__(256) void prep_kernel(
    const float* __restrict__ Wv, const float* __restrict__ Wout,
    const float* __restrict__ Woff, const float* __restrict__ Wa,
    const float* __restrict__ boff, const float* __restrict__ ba,
    ushort_t* __restrict__ WtV, ushort_t* __restrict__ WtO,
    ushort_t* __restrict__ Wcomb, float* __restrict__ bcomb,
    ushort_t* __restrict__ value)
{
    const int n = blockIdx.x, k = threadIdx.x;
    if (blockIdx.y == 0) {
        WtV[n * 256 + k] = f2bf(Wv[(size_t)k * 256 + n]);
    } else if (blockIdx.y == 1) {
        WtO[n * 256 + k] = f2bf(Wout[(size_t)k * 256 + n]);
    } else if (blockIdx.y == 2) {
        if (n < 96) {
            float w = (n < 64) ? Woff[(size_t)k * 64 + n] : Wa[(size_t)k * 32 + (n - 64)];
            Wcomb[n * 256 + k] = f2bf(w);
            if (k == 0) bcomb[n] = (n < 64) ? boff[n] : ba[n - 64];
        }
    } else {
        // border zeroing: map n (0..31 = b*8+h), 609 border pixels each
        if (n < BATCH * NH) {
            ushort_t* map = value + (size_t)n * PP * 32;
            for (int i = k; i < 609; i += 256) {
                int row, col;
                if (i < 309) {            // rows 0,101,102 full
                    int rr = i / 103;
                    row = (rr == 0) ? 0 : (rr == 1 ? 101 : 102);
                    col = i % 103;
                } else {                  // cols 0,101,102 for rows 1..100
                    int j = i - 309;
                    int cc = j / 100;
                    col = (cc == 0) ? 0 : (cc == 1 ? 101 : 102);
                    row = 1 + j % 100;
                }
                uint4* p = reinterpret_cast<uint4*>(map + (size_t)(row * PW + col) * 32);
                uint4 z = {0u, 0u, 0u, 0u};
                p[0] = z; p[1] = z; p[2] = z; p[3] = z;
            }
        }
    }
}

// ---------------------------------------------------------------------------
// MFMA GEMM: C = A[M][256] @ W + bias. Wt = W^T bf16 [n][k].
// BM=64, BN=256, BK=32; 4 waves, wave w owns cols w*64..+63 (4x4 frags).
// OUT_MODE: 0 = f32 row-major, 2 = bf16 padded head-major value layout.
// ---------------------------------------------------------------------------
template<bool IN_BF16, int OUT_MODE>
__global__ __launch_bounds__(256) void gemm_mfma_kernel(
    const void* __restrict__ Ain, const ushort_t* __restrict__ Wt,
    const float* __restrict__ bias, void* __restrict__ Cout)
{
    __shared__ ushort_t As[64 * 32];
    __shared__ ushort_t Bs[256 * 32];

    const int tid  = threadIdx.x;
    const int lane = tid & 63;
    const int wv   = tid >> 6;
    const int row0 = blockIdx.x * 64;

    const f32x4 zero = {0.f, 0.f, 0.f, 0.f};
    f32x4 acc[4][4];
    #pragma unroll
    for (int m = 0; m < 4; ++m)
        #pragma unroll
        for (int n = 0; n < 4; ++n) acc[m][n] = zero;

    const int ar  = tid >> 2;
    const int akb = tid & 3;
    const int asw = (akb ^ ((ar >> 1) & 3)) * 8;
    const int fr = lane & 15, kb = lane >> 4;

    for (int k0 = 0; k0 < 256; k0 += 32) {
        if (IN_BF16) {
            const ushort_t* A = (const ushort_t*)Ain;
            uint4 v = *reinterpret_cast<const uint4*>(
                &A[(size_t)(row0 + ar) * 256 + k0 + akb * 8]);
            *reinterpret_cast<uint4*>(&As[ar * 32 + asw]) = v;
        } else {
            const float* A = (const float*)Ain;
            const float* p = &A[(size_t)(row0 + ar) * 256 + k0 + akb * 8];
            float4 f0 = *reinterpret_cast<const float4*>(p);
            float4 f1 = *reinterpret_cast<const float4*>(p + 4);
            u16x8 pk;
            pk[0] = f2bf(f0.x); pk[1] = f2bf(f0.y);
            pk[2] = f2bf(f0.z); pk[3] = f2bf(f0.w);
            pk[4] = f2bf(f1.x); pk[5] = f2bf(f1.y);
            pk[6] = f2bf(f1.z); pk[7] = f2bf(f1.w);
            *reinterpret_cast<u16x8*>(&As[ar * 32 + asw]) = pk;
        }
        #pragma unroll
        for (int j = 0; j < 4; ++j) {
            int n = (tid >> 2) + 64 * j;
            uint4 v = *reinterpret_cast<const uint4*>(
                &Wt[(size_t)n * 256 + k0 + akb * 8]);
            *reinterpret_cast<uint4*>(
                &Bs[n * 32 + ((akb ^ ((n >> 1) & 3)) * 8)]) = v;
        }
        __syncthreads();

        bf16x8 af[4], bf[4];
        #pragma unroll
        for (int m = 0; m < 4; ++m) {
            int r = m * 16 + fr;
            af[m] = *reinterpret_cast<const bf16x8*>(
                &As[r * 32 + ((kb ^ ((r >> 1) & 3)) * 8)]);
        }
        #pragma unroll
        for (int n = 0; n < 4; ++n) {
            int c = wv * 64 + n * 16 + fr;
            bf[n] = *reinterpret_cast<const bf16x8*>(
                &Bs[c * 32 + ((kb ^ ((c >> 1) & 3)) * 8)]);
        }
        #pragma unroll
        for (int m = 0; m < 4; ++m)
            #pragma unroll
            for (int n = 0; n < 4; ++n)
                acc[m][n] = __builtin_amdgcn_mfma_f32_16x16x32_bf16(
                    af[m], bf[n], acc[m][n], 0, 0, 0);
        __syncthreads();
    }

    if (OUT_MODE == 0) {
        float* O = (float*)Cout;
        #pragma unroll
        for (int m = 0; m < 4; ++m)
            #pragma unroll
            for (int n = 0; n < 4; ++n) {
                int c = wv * 64 + n * 16 + fr;
                float bb = bias[c];
                #pragma unroll
                for (int j = 0; j < 4; ++j) {
                    int r = row0 + m * 16 + kb * 4 + j;
                    O[(size_t)r * 256 + c] = acc[m][n][j] + bb;
                }
            }
    } else {
        // padded head-major bf16: [(b*8+h)*PP + (y+1)*PW + (x+1)]*32 + (c&31)
        ushort_t* O = (ushort_t*)Cout;
        #pragma unroll
        for (int m = 0; m < 4; ++m) {
            #pragma unroll
            for (int j = 0; j < 4; ++j) {
                int r = row0 + m * 16 + kb * 4 + j;
                int rb = (int)((unsigned)r / 10000u);
                int pr = r - rb * 10000;
                int y  = (int)((unsigned)pr / 100u);
                int x  = pr - y * 100;
                size_t base = ((size_t)rb * 8) * PP + (size_t)(y + 1) * PW + (x + 1);
                #pragma unroll
                for (int n = 0; n < 4; ++n) {
                    int c = wv * 64 + n * 16 + fr;
                    float bb = bias[c];
                    size_t addr = (base + (size_t)(c >> 5) * PP) * 32 + (c & 31);
                    O[addr] = f2bf(acc[m][n][j] + bb);
                }
            }
        }
    }
}

// ---------------------------------------------------------------------------
// Projection GEMM: oaproj[M][96] = query[M][256] @ Wcomb^T + bcomb (f32 out).
// ---------------------------------------------------------------------------
__global__ __launch_bounds__(256) void gemm_proj_kernel(
    const float* __restrict__ A, const ushort_t* __restrict__ Wt,
    const float* __restrict__ bias, float* __restrict__ C)
{
    __shared__ ushort_t As[64 * 32];
    __shared__ ushort_t Bs[96 * 32];

    const int tid  = threadIdx.x;
    const int lane = tid & 63;
    const int wv   = tid >> 6;
    const int row0 = blockIdx.x * 64;

    const f32x4 zero = {0.f, 0.f, 0.f, 0.f};
    f32x4 acc[6];
    #pragma unroll
    for (int n = 0; n < 6; ++n) acc[n] = zero;

    const int ar  = tid >> 2;
    const int akb = tid & 3;
    const int asw = (akb ^ ((ar >> 1) & 3)) * 8;
    const int fr = lane & 15, kb = lane >> 4;

    for (int k0 = 0; k0 < 256; k0 += 32) {
        {
            const float* p = &A[(size_t)(row0 + ar) * 256 + k0 + akb * 8];
            float4 f0 = *reinterpret_cast<const float4*>(p);
            float4 f1 = *reinterpret_cast<const float4*>(p + 4);
            u16x8 pk;
            pk[0] = f2bf(f0.x); pk[1] = f2bf(f0.y);
            pk[2] = f2bf(f0.z); pk[3] = f2bf(f0.w);
            pk[4] = f2bf(f1.x); pk[5] = f2bf(f1.y);
            pk[6] = f2bf(f1.z); pk[7] = f2bf(f1.w);
            *reinterpret_cast<u16x8*>(&As[ar * 32 + asw]) = pk;
        }
        #pragma unroll
        for (int j = 0; j < 2; ++j) {
            int n = (tid >> 2) + 64 * j;
            if (n < 96) {
                uint4 v = *reinterpret_cast<const uint4*>(
                    &Wt[(size_t)n * 256 + k0 + akb * 8]);
                *reinterpret_cast<uint4*>(
                    &Bs[n * 32 + ((akb ^ ((n >> 1) & 3)) * 8)]) = v;
            }
        }
        __syncthreads();

        bf16x8 af;
        {
            int r = wv * 16 + fr;
            af = *reinterpret_cast<const bf16x8*>(
                &As[r * 32 + ((kb ^ ((r >> 1) & 3)) * 8)]);
        }
        #pragma unroll
        for (int n = 0; n < 6; ++n) {
            int c = n * 16 + fr;
            bf16x8 bf = *reinterpret_cast<const bf16x8*>(
                &Bs[c * 32 + ((kb ^ ((c >> 1) & 3)) * 8)]);
            acc[n] = __builtin_amdgcn_mfma_f32_16x16x32_bf16(
                af, bf, acc[n], 0, 0, 0);
        }
        __syncthreads();
    }

    #pragma unroll
    for (int n = 0; n < 6; ++n) {
        int c = n * 16 + fr;
        float bb = bias[c];
        #pragma unroll
        for (int j = 0; j < 4; ++j) {
            int r = row0 + wv * 16 + kb * 4 + j;
            C[(size_t)r * 96 + c] = acc[n][j] + bb;
        }
    }
}

// ---------------------------------------------------------------------------
// Deform: block = 32 queries x 4 heads (one (batch, head-half) slab).
// XCD affinity: xcd = blk&7 -> b = xcd>>1, hg = xcd&1; slab = 2.72 MB < L2.
// Padded map: x-adjacent corners are one 128B load (8 lanes x uint4);
// halves reduced via __shfl_xor(4). Out-of-range weight = 0 (border zeros).
// ---------------------------------------------------------------------------
__global__ __launch_bounds__(256) void deform_kernel(
    const float* __restrict__ oaproj, const float* __restrict__ refpts,
    const ushort_t* __restrict__ value, ushort_t* __restrict__ out)
{
    __shared__ int    spix[NP][128];   // padded top-left pixel
    __shared__ float4 swt [NP][128];   // {w00,w01,w10,w11} * attn

    const int blk = blockIdx.x;
    const int xcd = blk & 7;
    const int b = xcd >> 1, hg = xcd & 1;
    const int q0 = (blk >> 3) * 32;

    const int tid = threadIdx.x;

    if (tid < 128) {
        const int q = tid >> 2, hl = tid & 3;
        const int hh = hg * 4 + hl;
        const int qg = q0 + q;
        if (qg >= LQ) {
            float4 z = {0.f, 0.f, 0.f, 0.f};
            #pragma unroll
            for (int p = 0; p < NP; ++p) { spix[p][tid] = 0; swt[p][tid] = z; }
        } else {
            const size_t row = (size_t)b * LQ + qg;
            const float* oa = oaproj + row * 96;
            float4 l4 = *reinterpret_cast<const float4*>(oa + 64 + hh * 4);
            float mx = fmaxf(fmaxf(l4.x, l4.y), fmaxf(l4.z, l4.w));
            float e0 = __expf(l4.x - mx), e1 = __expf(l4.y - mx);
            float e2 = __expf(l4.z - mx), e3 = __expf(l4.w - mx);
            float inv = 1.f / (e0 + e1 + e2 + e3);
            float ew[4] = {e0 * inv, e1 * inv, e2 * inv, e3 * inv};
            float4 o0 = *reinterpret_cast<const float4*>(oa + hh * 8);
            float4 o1 = *reinterpret_cast<const float4*>(oa + hh * 8 + 4);
            float oxv[4] = {o0.x, o0.z, o1.x, o1.z};
            float oyv[4] = {o0.y, o0.w, o1.y, o1.w};
            const float* rp = refpts + row * 4;
            float cx = rp[0], cy = rp[1], rw = rp[2], rh = rp[3];
            #pragma unroll
            for (int p = 0; p < NP; ++p) {
                float x = (cx + oxv[p] * rw * 0.125f) * (float)HWD - 0.5f;
                float y = (cy + oyv[p] * rh * 0.125f) * (float)HWD - 0.5f;
                float x0f = floorf(x), y0f = floorf(y);
                float wx = x - x0f, wy = y - y0f;
                int x0 = (int)x0f, y0 = (int)y0f;
                float vx0 = (x0 >= 0 && x0 < HWD) ? 1.f : 0.f;
                float vx1 = (x0 + 1 >= 0 && x0 + 1 < HWD) ? 1.f : 0.f;
                float vy0 = (y0 >= 0 && y0 < HWD) ? 1.f : 0.f;
                float vy1 = (y0 + 1 >= 0 && y0 + 1 < HWD) ? 1.f : 0.f;
                int px = min(max(x0, -1), HWD) + 1;     // 0..101
                int py = min(max(y0, -1), HWD) + 1;     // 0..101
                float aw = ew[p];
                spix[p][tid] = py * PW + px;
                float4 wt = {aw * (1.f - wx) * (1.f - wy) * vx0 * vy0,
                             aw * wx * (1.f - wy) * vx1 * vy0,
                             aw * (1.f - wx) * wy * vx0 * vy1,
                             aw * wx * wy * vx1 * vy1};
                swt[p][tid] = wt;
            }
        }
    }
    __syncthreads();

    const int lane = tid & 63, wv = tid >> 6;
    const int g8 = lane >> 3, c16 = lane & 7;
    const bool rightHalf = (c16 >= 4);

    #pragma unroll
    for (int pass = 0; pass < 4; ++pass) {
        const int qh = pass * 32 + wv * 8 + g8;       // 0..127
        const int q = qh >> 2, hl = qh & 3;
        const int hh = hg * 4 + hl;
        const ushort_t* slab = value + (size_t)(b * 8 + hh) * PP * 32 + c16 * 8;

        int pix[NP]; float4 w4[NP];
        #pragma unroll
        for (int p = 0; p < NP; ++p) {
            pix[p] = spix[p][qh];
            w4[p]  = swt [p][qh];
        }
        uint4 vt[NP], vbm[NP];
        #pragma unroll
        for (int p = 0; p < NP; ++p) {
            vt[p]  = *reinterpret_cast<const uint4*>(slab + (size_t)pix[p] * 32);
            vbm[p] = *reinterpret_cast<const uint4*>(slab + (size_t)(pix[p] + PW) * 32);
        }
        float a0 = 0.f, a1 = 0.f, a2 = 0.f, a3 = 0.f;
        float a4 = 0.f, a5 = 0.f, a6 = 0.f, a7 = 0.f;
        #define ACC(V, W) { const float w_ = (W); const uint4 v_ = (V); \
            a0 += w_ * __uint_as_float(v_.x << 16); \
            a1 += w_ * __uint_as_float(v_.x & 0xffff0000u); \
            a2 += w_ * __uint_as_float(v_.y << 16); \
            a3 += w_ * __uint_as_float(v_.y & 0xffff0000u); \
            a4 += w_ * __uint_as_float(v_.z << 16); \
            a5 += w_ * __uint_as_float(v_.z & 0xffff0000u); \
            a6 += w_ * __uint_as_float(v_.w << 16); \
            a7 += w_ * __uint_as_float(v_.w & 0xffff0000u); }
        #pragma unroll
        for (int p = 0; p < NP; ++p) {
            float wt_ = rightHalf ? w4[p].y : w4[p].x;
            float wb_ = rightHalf ? w4[p].w : w4[p].z;
            ACC(vt[p],  wt_);
            ACC(vbm[p], wb_);
        }
        #undef ACC
        // combine left/right pixel halves (lane L <-> L^4)
        a0 += __shfl_xor(a0, 4); a1 += __shfl_xor(a1, 4);
        a2 += __shfl_xor(a2, 4); a3 += __shfl_xor(a3, 4);
        a4 += __shfl_xor(a4, 4); a5 += __shfl_xor(a5, 4);
        a6 += __shfl_xor(a6, 4); a7 += __shfl_xor(a7, 4);

        if (!rightHalf && (q0 + q) < LQ) {
            const size_t orow = (size_t)b * LQ + q0 + q;
            u16x8 pk;
            pk[0] = f2bf(a0); pk[1] = f2bf(a1);
            pk[2] = f2bf(a2); pk[3] = f2bf(a3);
            pk[4] = f2bf(a4); pk[5] = f2bf(a5);
            pk[6] = f2bf(a6); pk[7] = f2bf(a7);
            *reinterpret_cast<u16x8*>(
                &out[orow * 256 + hh * 32 + (c16 & 3) * 8]) = pk;
        }
    }
}

// ---------------------------------------------------------------------------
extern "C" void kernel_launch(void* const* d_in, const int* in_sizes, int n_in,
                              void* d_out, int out_size, void* d_ws, size_t ws_size,
                              hipStream_t stream)
{
    const float* query  = (const float*)d_in[0];
    const float* refpts = (const float*)d_in[1];
    const float* flat   = (const float*)d_in[2];
    const float* Wv   = (const float*)d_in[6];
    const float* bv   = (const float*)d_in[7];
    const float* Woff = (const float*)d_in[8];
    const float* boff = (const float*)d_in[9];
    const float* Wa   = (const float*)d_in[10];
    const float* ba   = (const float*)d_in[11];
    const float* Wout = (const float*)d_in[12];
    const float* bout = (const float*)d_in[13];
    float* out = (float*)d_out;

    const size_t MROWS = (size_t)BATCH * LIN;                 // 40000
    ushort_t* value  = (ushort_t*)d_ws;                       // B*8*PP*32 bf16 (21.7 MB)
    ushort_t* ws2    = value + (size_t)BATCH * NH * PP * 32;  // 40000x256 bf16
    ushort_t* WtV    = ws2 + MROWS * DM;                      // 256x256 bf16
    ushort_t* WtO    = WtV + 256 * 256;                       // 256x256 bf16
    ushort_t* Wcomb  = WtO + 256 * 256;                       // 96x256 bf16
    float*    bcomb  = (float*)(Wcomb + 96 * 256);            // 96 f32 (+pad)
    float*    oaproj = bcomb + 128;                           // 40000x96 f32

    dim3 blk(256);

    prep_kernel<<<dim3(256, 4), blk, 0, stream>>>(
        Wv, Wout, Woff, Wa, boff, ba, WtV, WtO, Wcomb, bcomb, value);

    gemm_mfma_kernel<false, 2><<<dim3(MROWS / 64), blk, 0, stream>>>(
        flat, WtV, bv, value);

    gemm_proj_kernel<<<dim3(MROWS / 64), blk, 0, stream>>>(
        query, Wcomb, bcomb, oaproj);

    deform_kernel<<<dim3(313 * 8), blk, 0, stream>>>(
        oaproj, refpts, value, ws2);

    gemm_mfma_kernel<true, 0><<<dim3(MROWS / 64), blk, 0, stream>>>(
        ws2, WtO, bout, out);
}

// Round 7
// 89.942 us; speedup vs baseline: 1.2136x; 1.2136x over previous
//
#include <hip/hip_runtime.h>

#define BATCH 4
#define LQ    10000
#define DM    256
#define NH    8
#define NP    4
#define HWD   100
#define LIN   10000

typedef unsigned short ushort_t;
typedef __attribute__((ext_vector_type(8))) short bf16x8;
typedef __attribute__((ext_vector_type(8))) unsigned short u16x8;
typedef __attribute__((ext_vector_type(4))) float f32x4;

__device__ __forceinline__ unsigned short f2bf(float f) {
    unsigned int u = __float_as_uint(f);
    u += 0x7FFFu + ((u >> 16) & 1u);          // round-to-nearest-even
    return (unsigned short)(u >> 16);
}

// ---------------------------------------------------------------------------
// Prep: WtV/WtO = bf16(W^T) 256x256; Wcomb[96][256] = bf16([Woff|Wa]^T);
// bcomb[96] = [boff|ba]. grid (256,3) x 256 threads.
// ---------------------------------------------------------------------------
__global__ __launch_bounds__(256) void prep_kernel(
    const float* __restrict__ Wv, const float* __restrict__ Wout,
    const float* __restrict__ Woff, const float* __restrict__ Wa,
    const float* __restrict__ boff, const float* __restrict__ ba,
    ushort_t* __restrict__ WtV, ushort_t* __restrict__ WtO,
    ushort_t* __restrict__ Wcomb, float* __restrict__ bcomb)
{
    const int n = blockIdx.x, k = threadIdx.x;
    if (blockIdx.y == 0) {
        WtV[n * 256 + k] = f2bf(Wv[(size_t)k * 256 + n]);
    } else if (blockIdx.y == 1) {
        WtO[n * 256 + k] = f2bf(Wout[(size_t)k * 256 + n]);
    } else if (n < 96) {
        float w = (n < 64) ? Woff[(size_t)k * 64 + n] : Wa[(size_t)k * 32 + (n - 64)];
        Wcomb[n * 256 + k] = f2bf(w);
        if (k == 0) bcomb[n] = (n < 64) ? boff[n] : ba[n - 64];
    }
}

// ---------------------------------------------------------------------------
// MFMA GEMM: C[M][256] = A[M][256] @ W + bias. Wt = W^T bf16 [n][k].
// BM=64, BN=256, BK=32; 4 waves, wave w owns cols w*64..+63 (4x4 frags).
// ---------------------------------------------------------------------------
template<bool IN_BF16, bool OUT_BF16>
__global__ __launch_bounds__(256) void gemm_mfma_kernel(
    const void* __restrict__ Ain, const ushort_t* __restrict__ Wt,
    const float* __restrict__ bias, void* __restrict__ Cout)
{
    __shared__ ushort_t As[64 * 32];
    __shared__ ushort_t Bs[256 * 32];

    const int tid  = threadIdx.x;
    const int lane = tid & 63;
    const int wv   = tid >> 6;
    const int row0 = blockIdx.x * 64;

    const f32x4 zero = {0.f, 0.f, 0.f, 0.f};
    f32x4 acc[4][4];
    #pragma unroll
    for (int m = 0; m < 4; ++m)
        #pragma unroll
        for (int n = 0; n < 4; ++n) acc[m][n] = zero;

    const int ar  = tid >> 2;
    const int akb = tid & 3;
    const int asw = (akb ^ ((ar >> 1) & 3)) * 8;
    const int fr = lane & 15, kb = lane >> 4;

    for (int k0 = 0; k0 < 256; k0 += 32) {
        if (IN_BF16) {
            const ushort_t* A = (const ushort_t*)Ain;
            uint4 v = *reinterpret_cast<const uint4*>(
                &A[(size_t)(row0 + ar) * 256 + k0 + akb * 8]);
            *reinterpret_cast<uint4*>(&As[ar * 32 + asw]) = v;
        } else {
            const float* A = (const float*)Ain;
            const float* p = &A[(size_t)(row0 + ar) * 256 + k0 + akb * 8];
            float4 f0 = *reinterpret_cast<const float4*>(p);
            float4 f1 = *reinterpret_cast<const float4*>(p + 4);
            u16x8 pk;
            pk[0] = f2bf(f0.x); pk[1] = f2bf(f0.y);
            pk[2] = f2bf(f0.z); pk[3] = f2bf(f0.w);
            pk[4] = f2bf(f1.x); pk[5] = f2bf(f1.y);
            pk[6] = f2bf(f1.z); pk[7] = f2bf(f1.w);
            *reinterpret_cast<u16x8*>(&As[ar * 32 + asw]) = pk;
        }
        #pragma unroll
        for (int j = 0; j < 4; ++j) {
            int n = (tid >> 2) + 64 * j;
            uint4 v = *reinterpret_cast<const uint4*>(
                &Wt[(size_t)n * 256 + k0 + akb * 8]);
            *reinterpret_cast<uint4*>(
                &Bs[n * 32 + ((akb ^ ((n >> 1) & 3)) * 8)]) = v;
        }
        __syncthreads();

        bf16x8 af[4], bf[4];
        #pragma unroll
        for (int m = 0; m < 4; ++m) {
            int r = m * 16 + fr;
            af[m] = *reinterpret_cast<const bf16x8*>(
                &As[r * 32 + ((kb ^ ((r >> 1) & 3)) * 8)]);
        }
        #pragma unroll
        for (int n = 0; n < 4; ++n) {
            int c = wv * 64 + n * 16 + fr;
            bf[n] = *reinterpret_cast<const bf16x8*>(
                &Bs[c * 32 + ((kb ^ ((c >> 1) & 3)) * 8)]);
        }
        #pragma unroll
        for (int m = 0; m < 4; ++m)
            #pragma unroll
            for (int n = 0; n < 4; ++n)
                acc[m][n] = __builtin_amdgcn_mfma_f32_16x16x32_bf16(
                    af[m], bf[n], acc[m][n], 0, 0, 0);
        __syncthreads();
    }

    #pragma unroll
    for (int m = 0; m < 4; ++m) {
        #pragma unroll
        for (int n = 0; n < 4; ++n) {
            int c = wv * 64 + n * 16 + fr;
            float bb = bias[c];
            #pragma unroll
            for (int j = 0; j < 4; ++j) {
                int r = row0 + m * 16 + kb * 4 + j;
                float v = acc[m][n][j] + bb;
                if (OUT_BF16)
                    ((ushort_t*)Cout)[(size_t)r * 256 + c] = f2bf(v);
                else
                    ((float*)Cout)[(size_t)r * 256 + c] = v;
            }
        }
    }
}

// ---------------------------------------------------------------------------
// Projection GEMM: oaproj[M][96] = query[M][256] @ Wcomb^T + bcomb (f32 out).
// ---------------------------------------------------------------------------
__global__ __launch_bounds__(256) void gemm_proj_kernel(
    const float* __restrict__ A, const ushort_t* __restrict__ Wt,
    const float* __restrict__ bias, float* __restrict__ C)
{
    __shared__ ushort_t As[64 * 32];
    __shared__ ushort_t Bs[96 * 32];

    const int tid  = threadIdx.x;
    const int lane = tid & 63;
    const int wv   = tid >> 6;
    const int row0 = blockIdx.x * 64;

    const f32x4 zero = {0.f, 0.f, 0.f, 0.f};
    f32x4 acc[6];
    #pragma unroll
    for (int n = 0; n < 6; ++n) acc[n] = zero;

    const int ar  = tid >> 2;
    const int akb = tid & 3;
    const int asw = (akb ^ ((ar >> 1) & 3)) * 8;
    const int fr = lane & 15, kb = lane >> 4;

    for (int k0 = 0; k0 < 256; k0 += 32) {
        {
            const float* p = &A[(size_t)(row0 + ar) * 256 + k0 + akb * 8];
            float4 f0 = *reinterpret_cast<const float4*>(p);
            float4 f1 = *reinterpret_cast<const float4*>(p + 4);
            u16x8 pk;
            pk[0] = f2bf(f0.x); pk[1] = f2bf(f0.y);
            pk[2] = f2bf(f0.z); pk[3] = f2bf(f0.w);
            pk[4] = f2bf(f1.x); pk[5] = f2bf(f1.y);
            pk[6] = f2bf(f1.z); pk[7] = f2bf(f1.w);
            *reinterpret_cast<u16x8*>(&As[ar * 32 + asw]) = pk;
        }
        #pragma unroll
        for (int j = 0; j < 2; ++j) {
            int n = (tid >> 2) + 64 * j;
            if (n < 96) {
                uint4 v = *reinterpret_cast<const uint4*>(
                    &Wt[(size_t)n * 256 + k0 + akb * 8]);
                *reinterpret_cast<uint4*>(
                    &Bs[n * 32 + ((akb ^ ((n >> 1) & 3)) * 8)]) = v;
            }
        }
        __syncthreads();

        bf16x8 af;
        {
            int r = wv * 16 + fr;
            af = *reinterpret_cast<const bf16x8*>(
                &As[r * 32 + ((kb ^ ((r >> 1) & 3)) * 8)]);
        }
        #pragma unroll
        for (int n = 0; n < 6; ++n) {
            int c = n * 16 + fr;
            bf16x8 bf = *reinterpret_cast<const bf16x8*>(
                &Bs[c * 32 + ((kb ^ ((c >> 1) & 3)) * 8)]);
            acc[n] = __builtin_amdgcn_mfma_f32_16x16x32_bf16(
                af, bf, acc[n], 0, 0, 0);
        }
        __syncthreads();
    }

    #pragma unroll
    for (int n = 0; n < 6; ++n) {
        int c = n * 16 + fr;
        float bb = bias[c];
        #pragma unroll
        for (int j = 0; j < 4; ++j) {
            int r = row0 + wv * 16 + kb * 4 + j;
            C[(size_t)r * 96 + c] = acc[n][j] + bb;
        }
    }
}

// ---------------------------------------------------------------------------
// Deform: oaproj -> softmax/coords (LDS) -> register-batched wide gathers ->
// ws2 bf16. Block = 16 queries of ONE batch, 256 threads.
// __launch_bounds__(256, 4): VGPR cap 128 so all 16 gather uint4s (64 VGPR)
// stay in flight -- at 40-72 VGPR the compiler serializes the load batch and
// the kernel becomes latency-bound (R6 post-mortem: 60us @ VGPR=40).
// XCD-affinity: grid 2504 = 313*8; xcd = blk&7 -> batch b = xcd>>1.
// ---------------------------------------------------------------------------
__global__ __launch_bounds__(256, 4) void deform_kernel(
    const float* __restrict__ oaproj, const float* __restrict__ refpts,
    const ushort_t* __restrict__ value, ushort_t* __restrict__ out)
{
    __shared__ int4   soff[NP * 128];   // [p][q*8+h] clamped y*100+x (4 corners)
    __shared__ float4 swt [NP * 128];   // [p][q*8+h] attn*bilerp*valid

    const int blk = blockIdx.x;
    const int xcd = blk & 7;
    const int b = xcd >> 1;
    const int qchunk = (blk >> 3) * 2 + (xcd & 1);
    if (qchunk >= LQ / 16) return;      // uniform over the block
    const int q0 = qchunk * 16;

    const int tid = threadIdx.x;

    if (tid < 128) {
        const int ql = tid >> 3, h = tid & 7;
        const size_t row = (size_t)(b * LQ + q0 + ql);
        const float* oa = oaproj + row * 96;
        float4 l4 = *reinterpret_cast<const float4*>(oa + 64 + h * 4);
        float mx = fmaxf(fmaxf(l4.x, l4.y), fmaxf(l4.z, l4.w));
        float e0 = __expf(l4.x - mx), e1 = __expf(l4.y - mx);
        float e2 = __expf(l4.z - mx), e3 = __expf(l4.w - mx);
        float inv = 1.f / (e0 + e1 + e2 + e3);
        float ew[4] = {e0 * inv, e1 * inv, e2 * inv, e3 * inv};
        float4 o0 = *reinterpret_cast<const float4*>(oa + h * 8);
        float4 o1 = *reinterpret_cast<const float4*>(oa + h * 8 + 4);
        float oxv[4] = {o0.x, o0.z, o1.x, o1.z};
        float oyv[4] = {o0.y, o0.w, o1.y, o1.w};
        const float* rp = refpts + row * 4;
        float cx = rp[0], cy = rp[1], rw = rp[2], rh = rp[3];
        #pragma unroll
        for (int p = 0; p < NP; ++p) {
            float x = (cx + oxv[p] * rw * 0.125f) * (float)HWD - 0.5f;
            float y = (cy + oyv[p] * rh * 0.125f) * (float)HWD - 0.5f;
            float x0f = floorf(x), y0f = floorf(y);
            float wx = x - x0f, wy = y - y0f;
            int x0 = (int)x0f, y0 = (int)y0f;
            int x1 = x0 + 1, y1 = y0 + 1;
            float vx0 = (x0 >= 0 && x0 < HWD) ? 1.f : 0.f;
            float vx1 = (x1 >= 0 && x1 < HWD) ? 1.f : 0.f;
            float vy0 = (y0 >= 0 && y0 < HWD) ? 1.f : 0.f;
            float vy1 = (y1 >= 0 && y1 < HWD) ? 1.f : 0.f;
            int cx0 = min(max(x0, 0), HWD - 1), cx1 = min(max(x1, 0), HWD - 1);
            int cy0 = min(max(y0, 0), HWD - 1), cy1 = min(max(y1, 0), HWD - 1);
            float aw = ew[p];
            int4 of = {cy0 * HWD + cx0, cy0 * HWD + cx1,
                       cy1 * HWD + cx0, cy1 * HWD + cx1};
            float4 wt = {aw * (1.f - wx) * (1.f - wy) * vx0 * vy0,
                         aw * wx * (1.f - wy) * vx1 * vy0,
                         aw * (1.f - wx) * wy * vx0 * vy1,
                         aw * wx * wy * vx1 * vy1};
            soff[p * 128 + tid] = of;
            swt [p * 128 + tid] = wt;
        }
    }
    __syncthreads();

    const int wv = tid >> 6, lane = tid & 63;
    const int c8 = lane & 3, s = lane >> 2;
    const int h_g = s & 7, qpair = s >> 3;
    const int chan = h_g * 32 + c8 * 8;
    const ushort_t* vb = value + (size_t)b * (LIN * 256) + chan;

    #pragma unroll
    for (int pass = 0; pass < 2; ++pass) {
        const int q = wv * 4 + pass * 2 + qpair;   // 0..15
        const int qh = q * 8 + h_g;

        int4 of[4]; float4 w4[4];
        #pragma unroll
        for (int p = 0; p < NP; ++p) {
            of[p] = soff[p * 128 + qh];
            w4[p] = swt [p * 128 + qh];
        }
        // 16 independent loads in flight, then accumulate
        uint4 vv[4][4];
        #pragma unroll
        for (int p = 0; p < NP; ++p) {
            vv[p][0] = *reinterpret_cast<const uint4*>(vb + ((size_t)of[p].x << 8));
            vv[p][1] = *reinterpret_cast<const uint4*>(vb + ((size_t)of[p].y << 8));
            vv[p][2] = *reinterpret_cast<const uint4*>(vb + ((size_t)of[p].z << 8));
            vv[p][3] = *reinterpret_cast<const uint4*>(vb + ((size_t)of[p].w << 8));
        }
        float a0 = 0.f, a1 = 0.f, a2 = 0.f, a3 = 0.f;
        float a4 = 0.f, a5 = 0.f, a6 = 0.f, a7 = 0.f;
        #define ACC(V, W) { const float w_ = (W); const uint4 v_ = (V); \
            a0 += w_ * __uint_as_float(v_.x << 16); \
            a1 += w_ * __uint_as_float(v_.x & 0xffff0000u); \
            a2 += w_ * __uint_as_float(v_.y << 16); \
            a3 += w_ * __uint_as_float(v_.y & 0xffff0000u); \
            a4 += w_ * __uint_as_float(v_.z << 16); \
            a5 += w_ * __uint_as_float(v_.z & 0xffff0000u); \
            a6 += w_ * __uint_as_float(v_.w << 16); \
            a7 += w_ * __uint_as_float(v_.w & 0xffff0000u); }
        #pragma unroll
        for (int p = 0; p < NP; ++p) {
            ACC(vv[p][0], w4[p].x);
            ACC(vv[p][1], w4[p].y);
            ACC(vv[p][2], w4[p].z);
            ACC(vv[p][3], w4[p].w);
        }
        #undef ACC

        const size_t orow = (size_t)(b * LQ + q0 + q);
        u16x8 pk;
        pk[0] = f2bf(a0); pk[1] = f2bf(a1);
        pk[2] = f2bf(a2); pk[3] = f2bf(a3);
        pk[4] = f2bf(a4); pk[5] = f2bf(a5);
        pk[6] = f2bf(a6); pk[7] = f2bf(a7);
        *reinterpret_cast<u16x8*>(&out[orow * 256 + chan]) = pk;
    }
}

// ---------------------------------------------------------------------------
extern "C" void kernel_launch(void* const* d_in, const int* in_sizes, int n_in,
                              void* d_out, int out_size, void* d_ws, size_t ws_size,
                              hipStream_t stream)
{
    const float* query  = (const float*)d_in[0];
    const float* refpts = (const float*)d_in[1];
    const float* flat   = (const float*)d_in[2];
    const float* Wv   = (const float*)d_in[6];
    const float* bv   = (const float*)d_in[7];
    const float* Woff = (const float*)d_in[8];
    const float* boff = (const float*)d_in[9];
    const float* Wa   = (const float*)d_in[10];
    const float* ba   = (const float*)d_in[11];
    const float* Wout = (const float*)d_in[12];
    const float* bout = (const float*)d_in[13];
    float* out = (float*)d_out;

    const size_t MROWS = (size_t)BATCH * LIN;            // 40000
    ushort_t* value  = (ushort_t*)d_ws;                  // 40000x256 bf16
    ushort_t* ws2    = value + MROWS * DM;               // 40000x256 bf16
    ushort_t* WtV    = ws2 + MROWS * DM;                 // 256x256 bf16
    ushort_t* WtO    = WtV + 256 * 256;                  // 256x256 bf16
    ushort_t* Wcomb  = WtO + 256 * 256;                  // 96x256 bf16
    float*    bcomb  = (float*)(Wcomb + 96 * 256);       // 96 f32 (+pad)
    float*    oaproj = bcomb + 128;                      // 40000x96 f32

    dim3 blk(256);

    prep_kernel<<<dim3(256, 3), blk, 0, stream>>>(
        Wv, Wout, Woff, Wa, boff, ba, WtV, WtO, Wcomb, bcomb);

    gemm_mfma_kernel<false, true><<<dim3(MROWS / 64), blk, 0, stream>>>(
        flat, WtV, bv, value);

    gemm_proj_kernel<<<dim3(MROWS / 64), blk, 0, stream>>>(
        query, Wcomb, bcomb, oaproj);

    deform_kernel<<<dim3(313 * 8), blk, 0, stream>>>(
        oaproj, refpts, value, ws2);

    gemm_mfma_kernel<true, false><<<dim3(MROWS / 64), blk, 0, stream>>>(
        ws2, WtO, bout, out);
}

// Round 8
// 84.310 us; speedup vs baseline: 1.2946x; 1.0668x over previous
//
#include <hip/hip_runtime.h>

#define BATCH 4
#define LQ    10000
#define DM    256
#define NH    8
#define NP    4
#define HWD   100
#define LIN   10000

typedef unsigned short ushort_t;
typedef __attribute__((ext_vector_type(8))) short bf16x8;
typedef __attribute__((ext_vector_type(8))) unsigned short u16x8;
typedef __attribute__((ext_vector_type(4))) float f32x4;

__device__ __forceinline__ unsigned short f2bf(float f) {
    unsigned int u = __float_as_uint(f);
    u += 0x7FFFu + ((u >> 16) & 1u);          // round-to-nearest-even
    return (unsigned short)(u >> 16);
}

// ---------------------------------------------------------------------------
// Prep: WtV/WtO = bf16(W^T) 256x256; Wcomb[96][256] = bf16([Woff|Wa]^T);
// bcomb[96] = [boff|ba]. grid (256,3) x 256 threads.
// ---------------------------------------------------------------------------
__global__ __launch_bounds__(256) void prep_kernel(
    const float* __restrict__ Wv, const float* __restrict__ Wout,
    const float* __restrict__ Woff, const float* __restrict__ Wa,
    const float* __restrict__ boff, const float* __restrict__ ba,
    ushort_t* __restrict__ WtV, ushort_t* __restrict__ WtO,
    ushort_t* __restrict__ Wcomb, float* __restrict__ bcomb)
{
    const int n = blockIdx.x, k = threadIdx.x;
    if (blockIdx.y == 0) {
        WtV[n * 256 + k] = f2bf(Wv[(size_t)k * 256 + n]);
    } else if (blockIdx.y == 1) {
        WtO[n * 256 + k] = f2bf(Wout[(size_t)k * 256 + n]);
    } else if (n < 96) {
        float w = (n < 64) ? Woff[(size_t)k * 64 + n] : Wa[(size_t)k * 32 + (n - 64)];
        Wcomb[n * 256 + k] = f2bf(w);
        if (k == 0) bcomb[n] = (n < 64) ? boff[n] : ba[n - 64];
    }
}

// ---------------------------------------------------------------------------
// Combined input GEMMs, one launch (saves a dispatch gap):
//   bid <  625 : value_hm[((b*8+h)*LIN + pix)*32 + ch] = bf16(flat @ Wv + bv)
//   bid >= 625 : oaproj[M][96] = f32(query @ [Woff|Wa]^T + bcomb)
// Both: BM=64, BK=32, 4 waves, LDS chunk-XOR swizzle (2-way max, free).
// ---------------------------------------------------------------------------
__global__ __launch_bounds__(256) void gemm_in_kernel(
    const float* __restrict__ flat, const float* __restrict__ query,
    const ushort_t* __restrict__ WtV, const ushort_t* __restrict__ Wcomb,
    const float* __restrict__ bv, const float* __restrict__ bcomb,
    ushort_t* __restrict__ value, float* __restrict__ oaproj)
{
    __shared__ ushort_t As[64 * 32];
    __shared__ ushort_t Bs[256 * 32];

    const int tid  = threadIdx.x;
    const int lane = tid & 63;
    const int wv   = tid >> 6;

    const int ar  = tid >> 2;
    const int akb = tid & 3;
    const int asw = (akb ^ ((ar >> 1) & 3)) * 8;
    const int fr = lane & 15, kb = lane >> 4;

    if (blockIdx.x < 625) {
        // ---------------- main value GEMM ----------------
        const int row0 = blockIdx.x * 64;
        const f32x4 zero = {0.f, 0.f, 0.f, 0.f};
        f32x4 acc[4][4];
        #pragma unroll
        for (int m = 0; m < 4; ++m)
            #pragma unroll
            for (int n = 0; n < 4; ++n) acc[m][n] = zero;

        for (int k0 = 0; k0 < 256; k0 += 32) {
            {
                const float* p = &flat[(size_t)(row0 + ar) * 256 + k0 + akb * 8];
                float4 f0 = *reinterpret_cast<const float4*>(p);
                float4 f1 = *reinterpret_cast<const float4*>(p + 4);
                u16x8 pk;
                pk[0] = f2bf(f0.x); pk[1] = f2bf(f0.y);
                pk[2] = f2bf(f0.z); pk[3] = f2bf(f0.w);
                pk[4] = f2bf(f1.x); pk[5] = f2bf(f1.y);
                pk[6] = f2bf(f1.z); pk[7] = f2bf(f1.w);
                *reinterpret_cast<u16x8*>(&As[ar * 32 + asw]) = pk;
            }
            #pragma unroll
            for (int j = 0; j < 4; ++j) {
                int n = (tid >> 2) + 64 * j;
                uint4 v = *reinterpret_cast<const uint4*>(
                    &WtV[(size_t)n * 256 + k0 + akb * 8]);
                *reinterpret_cast<uint4*>(
                    &Bs[n * 32 + ((akb ^ ((n >> 1) & 3)) * 8)]) = v;
            }
            __syncthreads();

            bf16x8 af[4], bf[4];
            #pragma unroll
            for (int m = 0; m < 4; ++m) {
                int r = m * 16 + fr;
                af[m] = *reinterpret_cast<const bf16x8*>(
                    &As[r * 32 + ((kb ^ ((r >> 1) & 3)) * 8)]);
            }
            #pragma unroll
            for (int n = 0; n < 4; ++n) {
                int c = wv * 64 + n * 16 + fr;
                bf[n] = *reinterpret_cast<const bf16x8*>(
                    &Bs[c * 32 + ((kb ^ ((c >> 1) & 3)) * 8)]);
            }
            #pragma unroll
            for (int m = 0; m < 4; ++m)
                #pragma unroll
                for (int n = 0; n < 4; ++n)
                    acc[m][n] = __builtin_amdgcn_mfma_f32_16x16x32_bf16(
                        af[m], bf[n], acc[m][n], 0, 0, 0);
            __syncthreads();
        }

        // epilogue -> head-major value layout
        #pragma unroll
        for (int n = 0; n < 4; ++n) {
            int c = wv * 64 + n * 16 + fr;
            float bb = bv[c];
            int hh = c >> 5, ch = c & 31;
            #pragma unroll
            for (int m = 0; m < 4; ++m) {
                #pragma unroll
                for (int j = 0; j < 4; ++j) {
                    int r = row0 + m * 16 + kb * 4 + j;
                    int rb = (int)((unsigned)r / 10000u);
                    int pix = r - rb * 10000;
                    size_t addr = (((size_t)(rb * 8 + hh)) * LIN + pix) * 32 + ch;
                    value[addr] = f2bf(acc[m][n][j] + bb);
                }
            }
        }
    } else {
        // ---------------- projection GEMM ----------------
        const int row0 = (blockIdx.x - 625) * 64;
        const f32x4 zero = {0.f, 0.f, 0.f, 0.f};
        f32x4 acc[6];
        #pragma unroll
        for (int n = 0; n < 6; ++n) acc[n] = zero;

        for (int k0 = 0; k0 < 256; k0 += 32) {
            {
                const float* p = &query[(size_t)(row0 + ar) * 256 + k0 + akb * 8];
                float4 f0 = *reinterpret_cast<const float4*>(p);
                float4 f1 = *reinterpret_cast<const float4*>(p + 4);
                u16x8 pk;
                pk[0] = f2bf(f0.x); pk[1] = f2bf(f0.y);
                pk[2] = f2bf(f0.z); pk[3] = f2bf(f0.w);
                pk[4] = f2bf(f1.x); pk[5] = f2bf(f1.y);
                pk[6] = f2bf(f1.z); pk[7] = f2bf(f1.w);
                *reinterpret_cast<u16x8*>(&As[ar * 32 + asw]) = pk;
            }
            #pragma unroll
            for (int j = 0; j < 2; ++j) {
                int n = (tid >> 2) + 64 * j;
                if (n < 96) {
                    uint4 v = *reinterpret_cast<const uint4*>(
                        &Wcomb[(size_t)n * 256 + k0 + akb * 8]);
                    *reinterpret_cast<uint4*>(
                        &Bs[n * 32 + ((akb ^ ((n >> 1) & 3)) * 8)]) = v;
                }
            }
            __syncthreads();

            bf16x8 af;
            {
                int r = wv * 16 + fr;
                af = *reinterpret_cast<const bf16x8*>(
                    &As[r * 32 + ((kb ^ ((r >> 1) & 3)) * 8)]);
            }
            #pragma unroll
            for (int n = 0; n < 6; ++n) {
                int c = n * 16 + fr;
                bf16x8 bf = *reinterpret_cast<const bf16x8*>(
                    &Bs[c * 32 + ((kb ^ ((c >> 1) & 3)) * 8)]);
                acc[n] = __builtin_amdgcn_mfma_f32_16x16x32_bf16(
                    af, bf, acc[n], 0, 0, 0);
            }
            __syncthreads();
        }

        #pragma unroll
        for (int n = 0; n < 6; ++n) {
            int c = n * 16 + fr;
            float bb = bcomb[c];
            #pragma unroll
            for (int j = 0; j < 4; ++j) {
                int r = row0 + wv * 16 + kb * 4 + j;
                oaproj[(size_t)r * 96 + c] = acc[n][j] + bb;
            }
        }
    }
}

// ---------------------------------------------------------------------------
// Deform: block = one (batch, head) map x 64 queries. value is head-major:
// each block's 16-uint4 gather batch hits ONE 640 KB slab -> L2-resident.
// XCD affinity: xcd = blk&7, 4 maps per XCD = 2.56 MB < 4 MB L2.
// Per-thread structure identical to R5 (16 loads in flight) -> bit-identical.
// ---------------------------------------------------------------------------
__global__ __launch_bounds__(256, 4) void deform_kernel(
    const float* __restrict__ oaproj, const float* __restrict__ refpts,
    const ushort_t* __restrict__ value, ushort_t* __restrict__ out)
{
    __shared__ int4   soff[NP * 64];    // [p][q] clamped y*100+x, 4 corners
    __shared__ float4 swt [NP * 64];    // [p][q] attn*bilerp*valid

    const int blk = blockIdx.x;
    const int xcd = blk & 7;
    const int sub = (blk >> 3) & 3;
    const int chunk = blk >> 5;          // 0..156
    const int map = xcd * 4 + sub;       // 0..31
    const int b = map >> 3, h = map & 7;
    const int q0 = chunk * 64;

    const int tid = threadIdx.x;

    if (tid < 64) {
        const int qg = q0 + tid;
        if (qg >= LQ) {
            int4 zi = {0, 0, 0, 0};
            float4 zf = {0.f, 0.f, 0.f, 0.f};
            #pragma unroll
            for (int p = 0; p < NP; ++p) { soff[p * 64 + tid] = zi; swt[p * 64 + tid] = zf; }
        } else {
            const size_t row = (size_t)b * LQ + qg;
            const float* oa = oaproj + row * 96;
            float4 l4 = *reinterpret_cast<const float4*>(oa + 64 + h * 4);
            float mx = fmaxf(fmaxf(l4.x, l4.y), fmaxf(l4.z, l4.w));
            float e0 = __expf(l4.x - mx), e1 = __expf(l4.y - mx);
            float e2 = __expf(l4.z - mx), e3 = __expf(l4.w - mx);
            float inv = 1.f / (e0 + e1 + e2 + e3);
            float ew[4] = {e0 * inv, e1 * inv, e2 * inv, e3 * inv};
            float4 o0 = *reinterpret_cast<const float4*>(oa + h * 8);
            float4 o1 = *reinterpret_cast<const float4*>(oa + h * 8 + 4);
            float oxv[4] = {o0.x, o0.z, o1.x, o1.z};
            float oyv[4] = {o0.y, o0.w, o1.y, o1.w};
            const float* rp = refpts + row * 4;
            float cx = rp[0], cy = rp[1], rw = rp[2], rh = rp[3];
            #pragma unroll
            for (int p = 0; p < NP; ++p) {
                float x = (cx + oxv[p] * rw * 0.125f) * (float)HWD - 0.5f;
                float y = (cy + oyv[p] * rh * 0.125f) * (float)HWD - 0.5f;
                float x0f = floorf(x), y0f = floorf(y);
                float wx = x - x0f, wy = y - y0f;
                int x0 = (int)x0f, y0 = (int)y0f;
                int x1 = x0 + 1, y1 = y0 + 1;
                float vx0 = (x0 >= 0 && x0 < HWD) ? 1.f : 0.f;
                float vx1 = (x1 >= 0 && x1 < HWD) ? 1.f : 0.f;
                float vy0 = (y0 >= 0 && y0 < HWD) ? 1.f : 0.f;
                float vy1 = (y1 >= 0 && y1 < HWD) ? 1.f : 0.f;
                int cx0 = min(max(x0, 0), HWD - 1), cx1 = min(max(x1, 0), HWD - 1);
                int cy0 = min(max(y0, 0), HWD - 1), cy1 = min(max(y1, 0), HWD - 1);
                float aw = ew[p];
                int4 of = {cy0 * HWD + cx0, cy0 * HWD + cx1,
                           cy1 * HWD + cx0, cy1 * HWD + cx1};
                float4 wt = {aw * (1.f - wx) * (1.f - wy) * vx0 * vy0,
                             aw * wx * (1.f - wy) * vx1 * vy0,
                             aw * (1.f - wx) * wy * vx0 * vy1,
                             aw * wx * wy * vx1 * vy1};
                soff[p * 64 + tid] = of;
                swt [p * 64 + tid] = wt;
            }
        }
    }
    __syncthreads();

    const int q = tid >> 2, c8 = tid & 3;
    const int qg = q0 + q;
    const ushort_t* vb = value + (size_t)map * (LIN * 32) + c8 * 8;

    int4 of[4]; float4 w4[4];
    #pragma unroll
    for (int p = 0; p < NP; ++p) {
        of[p] = soff[p * 64 + q];
        w4[p] = swt [p * 64 + q];
    }
    // 16 independent loads in flight, then accumulate (R5 order, bit-identical)
    uint4 vv[4][4];
    #pragma unroll
    for (int p = 0; p < NP; ++p) {
        vv[p][0] = *reinterpret_cast<const uint4*>(vb + ((size_t)of[p].x << 5));
        vv[p][1] = *reinterpret_cast<const uint4*>(vb + ((size_t)of[p].y << 5));
        vv[p][2] = *reinterpret_cast<const uint4*>(vb + ((size_t)of[p].z << 5));
        vv[p][3] = *reinterpret_cast<const uint4*>(vb + ((size_t)of[p].w << 5));
    }
    float a0 = 0.f, a1 = 0.f, a2 = 0.f, a3 = 0.f;
    float a4 = 0.f, a5 = 0.f, a6 = 0.f, a7 = 0.f;
    #define ACC(V, W) { const float w_ = (W); const uint4 v_ = (V); \
        a0 += w_ * __uint_as_float(v_.x << 16); \
        a1 += w_ * __uint_as_float(v_.x & 0xffff0000u); \
        a2 += w_ * __uint_as_float(v_.y << 16); \
        a3 += w_ * __uint_as_float(v_.y & 0xffff0000u); \
        a4 += w_ * __uint_as_float(v_.z << 16); \
        a5 += w_ * __uint_as_float(v_.z & 0xffff0000u); \
        a6 += w_ * __uint_as_float(v_.w << 16); \
        a7 += w_ * __uint_as_float(v_.w & 0xffff0000u); }
    #pragma unroll
    for (int p = 0; p < NP; ++p) {
        ACC(vv[p][0], w4[p].x);
        ACC(vv[p][1], w4[p].y);
        ACC(vv[p][2], w4[p].z);
        ACC(vv[p][3], w4[p].w);
    }
    #undef ACC

    if (qg < LQ) {
        const size_t orow = (size_t)b * LQ + qg;
        u16x8 pk;
        pk[0] = f2bf(a0); pk[1] = f2bf(a1);
        pk[2] = f2bf(a2); pk[3] = f2bf(a3);
        pk[4] = f2bf(a4); pk[5] = f2bf(a5);
        pk[6] = f2bf(a6); pk[7] = f2bf(a7);
        *reinterpret_cast<u16x8*>(&out[orow * 256 + h * 32 + c8 * 8]) = pk;
    }
}

// ---------------------------------------------------------------------------
// Output GEMM: out[M][256] = ws2 @ Wout + bout (f32). Same as R7.
// ---------------------------------------------------------------------------
__global__ __launch_bounds__(256) void gemm_out_kernel(
    const ushort_t* __restrict__ A, const ushort_t* __restrict__ Wt,
    const float* __restrict__ bias, float* __restrict__ Cout)
{
    __shared__ ushort_t As[64 * 32];
    __shared__ ushort_t Bs[256 * 32];

    const int tid  = threadIdx.x;
    const int lane = tid & 63;
    const int wv   = tid >> 6;
    const int row0 = blockIdx.x * 64;

    const f32x4 zero = {0.f, 0.f, 0.f, 0.f};
    f32x4 acc[4][4];
    #pragma unroll
    for (int m = 0; m < 4; ++m)
        #pragma unroll
        for (int n = 0; n < 4; ++n) acc[m][n] = zero;

    const int ar  = tid >> 2;
    const int akb = tid & 3;
    const int asw = (akb ^ ((ar >> 1) & 3)) * 8;
    const int fr = lane & 15, kb = lane >> 4;

    for (int k0 = 0; k0 < 256; k0 += 32) {
        {
            uint4 v = *reinterpret_cast<const uint4*>(
                &A[(size_t)(row0 + ar) * 256 + k0 + akb * 8]);
            *reinterpret_cast<uint4*>(&As[ar * 32 + asw]) = v;
        }
        #pragma unroll
        for (int j = 0; j < 4; ++j) {
            int n = (tid >> 2) + 64 * j;
            uint4 v = *reinterpret_cast<const uint4*>(
                &Wt[(size_t)n * 256 + k0 + akb * 8]);
            *reinterpret_cast<uint4*>(
                &Bs[n * 32 + ((akb ^ ((n >> 1) & 3)) * 8)]) = v;
        }
        __syncthreads();

        bf16x8 af[4], bf[4];
        #pragma unroll
        for (int m = 0; m < 4; ++m) {
            int r = m * 16 + fr;
            af[m] = *reinterpret_cast<const bf16x8*>(
                &As[r * 32 + ((kb ^ ((r >> 1) & 3)) * 8)]);
        }
        #pragma unroll
        for (int n = 0; n < 4; ++n) {
            int c = wv * 64 + n * 16 + fr;
            bf[n] = *reinterpret_cast<const bf16x8*>(
                &Bs[c * 32 + ((kb ^ ((c >> 1) & 3)) * 8)]);
        }
        #pragma unroll
        for (int m = 0; m < 4; ++m)
            #pragma unroll
            for (int n = 0; n < 4; ++n)
                acc[m][n] = __builtin_amdgcn_mfma_f32_16x16x32_bf16(
                    af[m], bf[n], acc[m][n], 0, 0, 0);
        __syncthreads();
    }

    #pragma unroll
    for (int m = 0; m < 4; ++m) {
        #pragma unroll
        for (int n = 0; n < 4; ++n) {
            int c = wv * 64 + n * 16 + fr;
            float bb = bias[c];
            #pragma unroll
            for (int j = 0; j < 4; ++j) {
                int r = row0 + m * 16 + kb * 4 + j;
                Cout[(size_t)r * 256 + c] = acc[m][n][j] + bb;
            }
        }
    }
}

// ---------------------------------------------------------------------------
extern "C" void kernel_launch(void* const* d_in, const int* in_sizes, int n_in,
                              void* d_out, int out_size, void* d_ws, size_t ws_size,
                              hipStream_t stream)
{
    const float* query  = (const float*)d_in[0];
    const float* refpts = (const float*)d_in[1];
    const float* flat   = (const float*)d_in[2];
    const float* Wv   = (const float*)d_in[6];
    const float* bv   = (const float*)d_in[7];
    const float* Woff = (const float*)d_in[8];
    const float* boff = (const float*)d_in[9];
    const float* Wa   = (const float*)d_in[10];
    const float* ba   = (const float*)d_in[11];
    const float* Wout = (const float*)d_in[12];
    const float* bout = (const float*)d_in[13];
    float* out = (float*)d_out;

    const size_t MROWS = (size_t)BATCH * LIN;            // 40000
    ushort_t* value  = (ushort_t*)d_ws;                  // [b][h][pix][32] bf16
    ushort_t* ws2    = value + MROWS * DM;               // 40000x256 bf16
    ushort_t* WtV    = ws2 + MROWS * DM;                 // 256x256 bf16
    ushort_t* WtO    = WtV + 256 * 256;                  // 256x256 bf16
    ushort_t* Wcomb  = WtO + 256 * 256;                  // 96x256 bf16
    float*    bcomb  = (float*)(Wcomb + 96 * 256);       // 96 f32 (+pad)
    float*    oaproj = bcomb + 128;                      // 40000x96 f32

    dim3 blk(256);

    prep_kernel<<<dim3(256, 3), blk, 0, stream>>>(
        Wv, Wout, Woff, Wa, boff, ba, WtV, WtO, Wcomb, bcomb);

    gemm_in_kernel<<<dim3(1250), blk, 0, stream>>>(
        flat, query, WtV, Wcomb, bv, bcomb, value, oaproj);

    deform_kernel<<<dim3(157 * 32), blk, 0, stream>>>(
        oaproj, refpts, value, ws2);

    gemm_out_kernel<<<dim3(MROWS / 64), blk, 0, stream>>>(
        ws2, WtO, bout, out);
}

// Round 9
// 72.705 us; speedup vs baseline: 1.5012x; 1.1596x over previous
//
#include <hip/hip_runtime.h>

#define BATCH 4
#define LQ    10000
#define DM    256
#define NH    8
#define NP    4
#define HWD   100
#define LIN   10000

typedef unsigned short ushort_t;
typedef __attribute__((ext_vector_type(8))) short bf16x8;
typedef __attribute__((ext_vector_type(8))) unsigned short u16x8;
typedef __attribute__((ext_vector_type(4))) float f32x4;

__device__ __forceinline__ unsigned short f2bf(float f) {
    unsigned int u = __float_as_uint(f);
    u += 0x7FFFu + ((u >> 16) & 1u);          // round-to-nearest-even
    return (unsigned short)(u >> 16);
}

// async global->LDS, 16B per lane. LDS dest = wave-uniform base + lane*16.
__device__ __forceinline__ void gload16(const ushort_t* g, ushort_t* l) {
    __builtin_amdgcn_global_load_lds(
        (const __attribute__((address_space(1))) void*)g,
        (__attribute__((address_space(3))) void*)l, 16, 0, 0);
}

// Swizzled weight storage: within each 64-k tile (8 chunks of 8 bf16),
// storage chunk ct = lc ^ ((n>>1)&7).  Frag reads use the same XOR ->
// ds_read_b128 lands 2-way max (free).  Linear-copy staging via gload16.
// ---------------------------------------------------------------------------
// Prep: swizzled WtV/WtO (256x256), Wcomb (96x256) + bcomb. grid (256,3).
// ---------------------------------------------------------------------------
__global__ __launch_bounds__(256) void prep_kernel(
    const float* __restrict__ Wv, const float* __restrict__ Wout,
    const float* __restrict__ Woff, const float* __restrict__ Wa,
    const float* __restrict__ boff, const float* __restrict__ ba,
    ushort_t* __restrict__ WtV, ushort_t* __restrict__ WtO,
    ushort_t* __restrict__ Wcomb, float* __restrict__ bcomb)
{
    const int n = blockIdx.x, k = threadIdx.x;
    const int t = k >> 6, lc = (k >> 3) & 7, j = k & 7;
    const int ct = lc ^ ((n >> 1) & 7);
    const size_t addr = (size_t)n * 256 + t * 64 + ct * 8 + j;
    if (blockIdx.y == 0) {
        WtV[addr] = f2bf(Wv[(size_t)k * 256 + n]);
    } else if (blockIdx.y == 1) {
        WtO[addr] = f2bf(Wout[(size_t)k * 256 + n]);
    } else if (n < 96) {
        float w = (n < 64) ? Woff[(size_t)k * 64 + n] : Wa[(size_t)k * 32 + (n - 64)];
        Wcomb[addr] = f2bf(w);
        if (k == 0) bcomb[n] = (n < 64) ? boff[n] : ba[n - 64];
    }
}

// ---------------------------------------------------------------------------
// Combined input GEMMs (BM=64, BK=64, 4 waves):
//   bid <  625 : value_hm[((b*8+h)*LIN+pix)*32+ch] = bf16(flat @ Wv + bv)
//   bid >= 625 : oaproj[M][96] = f32(query @ [Woff|Wa]^T + bcomb)
// B staged via gload16 (pre-swizzled weights); A reg-staged (f32->bf16).
// ---------------------------------------------------------------------------
__global__ __launch_bounds__(256) void gemm_in_kernel(
    const float* __restrict__ flat, const float* __restrict__ query,
    const ushort_t* __restrict__ WtV, const ushort_t* __restrict__ Wcomb,
    const float* __restrict__ bv, const float* __restrict__ bcomb,
    ushort_t* __restrict__ value, float* __restrict__ oaproj)
{
    __shared__ ushort_t As[64 * 64];     // 8 KB
    __shared__ ushort_t Bs[256 * 64];    // 32 KB

    const int tid  = threadIdx.x;
    const int lane = tid & 63;
    const int wv   = tid >> 6;

    const int ar  = tid >> 2;            // A staging row
    const int akb = tid & 3;             // A staging chunk (0..3, +4)
    const int as_ = (ar >> 1) & 7;
    const int fr = lane & 15, kb = lane >> 4;
    const int ln8 = lane >> 3, lc8 = lane & 7;   // B staging decomposition

    if (blockIdx.x < 625) {
        // ---------------- value GEMM ----------------
        const int row0 = blockIdx.x * 64;
        const f32x4 zero = {0.f, 0.f, 0.f, 0.f};
        f32x4 acc[4][4];
        #pragma unroll
        for (int m = 0; m < 4; ++m)
            #pragma unroll
            for (int n = 0; n < 4; ++n) acc[m][n] = zero;

        for (int k0 = 0; k0 < 256; k0 += 64) {
            const int t = k0 >> 6;
            // B: 32 wave-loads, linear copy of pre-swizzled WtV
            #pragma unroll
            for (int it = 0; it < 8; ++it) {
                int r0 = (it * 4 + wv) * 8;
                gload16(&WtV[(size_t)(r0 + ln8) * 256 + t * 64 + lc8 * 8],
                        &Bs[r0 * 64]);
            }
            // A: reg-staged f32->bf16, swizzled LDS writes
            {
                const float* p = &flat[(size_t)(row0 + ar) * 256 + k0 + akb * 8];
                float4 f0 = *reinterpret_cast<const float4*>(p);
                float4 f1 = *reinterpret_cast<const float4*>(p + 4);
                u16x8 pk;
                pk[0] = f2bf(f0.x); pk[1] = f2bf(f0.y);
                pk[2] = f2bf(f0.z); pk[3] = f2bf(f0.w);
                pk[4] = f2bf(f1.x); pk[5] = f2bf(f1.y);
                pk[6] = f2bf(f1.z); pk[7] = f2bf(f1.w);
                *reinterpret_cast<u16x8*>(&As[ar * 64 + ((akb ^ as_) * 8)]) = pk;
                f0 = *reinterpret_cast<const float4*>(p + 32);
                f1 = *reinterpret_cast<const float4*>(p + 36);
                pk[0] = f2bf(f0.x); pk[1] = f2bf(f0.y);
                pk[2] = f2bf(f0.z); pk[3] = f2bf(f0.w);
                pk[4] = f2bf(f1.x); pk[5] = f2bf(f1.y);
                pk[6] = f2bf(f1.z); pk[7] = f2bf(f1.w);
                *reinterpret_cast<u16x8*>(&As[ar * 64 + (((akb + 4) ^ as_) * 8)]) = pk;
            }
            __syncthreads();

            #pragma unroll
            for (int ks = 0; ks < 2; ++ks) {
                const int lc = ks * 4 + kb;
                bf16x8 af[4], bf[4];
                #pragma unroll
                for (int m = 0; m < 4; ++m) {
                    int r = m * 16 + fr;
                    af[m] = *reinterpret_cast<const bf16x8*>(
                        &As[r * 64 + ((lc ^ ((r >> 1) & 7)) * 8)]);
                }
                #pragma unroll
                for (int n = 0; n < 4; ++n) {
                    int c = wv * 64 + n * 16 + fr;
                    bf[n] = *reinterpret_cast<const bf16x8*>(
                        &Bs[c * 64 + ((lc ^ ((c >> 1) & 7)) * 8)]);
                }
                #pragma unroll
                for (int m = 0; m < 4; ++m)
                    #pragma unroll
                    for (int n = 0; n < 4; ++n)
                        acc[m][n] = __builtin_amdgcn_mfma_f32_16x16x32_bf16(
                            af[m], bf[n], acc[m][n], 0, 0, 0);
            }
            __syncthreads();
        }

        // epilogue -> head-major value layout
        #pragma unroll
        for (int n = 0; n < 4; ++n) {
            int c = wv * 64 + n * 16 + fr;
            float bb = bv[c];
            int hh = c >> 5, ch = c & 31;
            #pragma unroll
            for (int m = 0; m < 4; ++m) {
                #pragma unroll
                for (int j = 0; j < 4; ++j) {
                    int r = row0 + m * 16 + kb * 4 + j;
                    int rb = (int)((unsigned)r / 10000u);
                    int pix = r - rb * 10000;
                    size_t addr = (((size_t)(rb * 8 + hh)) * LIN + pix) * 32 + ch;
                    value[addr] = f2bf(acc[m][n][j] + bb);
                }
            }
        }
    } else {
        // ---------------- projection GEMM ----------------
        const int row0 = (blockIdx.x - 625) * 64;
        const f32x4 zero = {0.f, 0.f, 0.f, 0.f};
        f32x4 acc[6];
        #pragma unroll
        for (int n = 0; n < 6; ++n) acc[n] = zero;

        for (int k0 = 0; k0 < 256; k0 += 64) {
            const int t = k0 >> 6;
            #pragma unroll
            for (int it = 0; it < 3; ++it) {
                int r0 = (it * 4 + wv) * 8;
                gload16(&Wcomb[(size_t)(r0 + ln8) * 256 + t * 64 + lc8 * 8],
                        &Bs[r0 * 64]);
            }
            {
                const float* p = &query[(size_t)(row0 + ar) * 256 + k0 + akb * 8];
                float4 f0 = *reinterpret_cast<const float4*>(p);
                float4 f1 = *reinterpret_cast<const float4*>(p + 4);
                u16x8 pk;
                pk[0] = f2bf(f0.x); pk[1] = f2bf(f0.y);
                pk[2] = f2bf(f0.z); pk[3] = f2bf(f0.w);
                pk[4] = f2bf(f1.x); pk[5] = f2bf(f1.y);
                pk[6] = f2bf(f1.z); pk[7] = f2bf(f1.w);
                *reinterpret_cast<u16x8*>(&As[ar * 64 + ((akb ^ as_) * 8)]) = pk;
                f0 = *reinterpret_cast<const float4*>(p + 32);
                f1 = *reinterpret_cast<const float4*>(p + 36);
                pk[0] = f2bf(f0.x); pk[1] = f2bf(f0.y);
                pk[2] = f2bf(f0.z); pk[3] = f2bf(f0.w);
                pk[4] = f2bf(f1.x); pk[5] = f2bf(f1.y);
                pk[6] = f2bf(f1.z); pk[7] = f2bf(f1.w);
                *reinterpret_cast<u16x8*>(&As[ar * 64 + (((akb + 4) ^ as_) * 8)]) = pk;
            }
            __syncthreads();

            #pragma unroll
            for (int ks = 0; ks < 2; ++ks) {
                const int lc = ks * 4 + kb;
                bf16x8 af;
                {
                    int r = wv * 16 + fr;
                    af = *reinterpret_cast<const bf16x8*>(
                        &As[r * 64 + ((lc ^ ((r >> 1) & 7)) * 8)]);
                }
                #pragma unroll
                for (int n = 0; n < 6; ++n) {
                    int c = n * 16 + fr;
                    bf16x8 bf = *reinterpret_cast<const bf16x8*>(
                        &Bs[c * 64 + ((lc ^ ((c >> 1) & 7)) * 8)]);
                    acc[n] = __builtin_amdgcn_mfma_f32_16x16x32_bf16(
                        af, bf, acc[n], 0, 0, 0);
                }
            }
            __syncthreads();
        }

        #pragma unroll
        for (int n = 0; n < 6; ++n) {
            int c = n * 16 + fr;
            float bb = bcomb[c];
            #pragma unroll
            for (int j = 0; j < 4; ++j) {
                int r = row0 + wv * 16 + kb * 4 + j;
                oaproj[(size_t)r * 96 + c] = acc[n][j] + bb;
            }
        }
    }
}

// ---------------------------------------------------------------------------
// Deform (R8 structure, L2-resident per-map gather). Only change: ws2 store
// is chunk-XOR pre-swizzled so gemm_out can stage it with gload16.
// ---------------------------------------------------------------------------
__global__ __launch_bounds__(256, 4) void deform_kernel(
    const float* __restrict__ oaproj, const float* __restrict__ refpts,
    const ushort_t* __restrict__ value, ushort_t* __restrict__ out)
{
    __shared__ int4   soff[NP * 64];
    __shared__ float4 swt [NP * 64];

    const int blk = blockIdx.x;
    const int xcd = blk & 7;
    const int sub = (blk >> 3) & 3;
    const int chunk = blk >> 5;
    const int map = xcd * 4 + sub;
    const int b = map >> 3, h = map & 7;
    const int q0 = chunk * 64;

    const int tid = threadIdx.x;

    if (tid < 64) {
        const int qg = q0 + tid;
        if (qg >= LQ) {
            int4 zi = {0, 0, 0, 0};
            float4 zf = {0.f, 0.f, 0.f, 0.f};
            #pragma unroll
            for (int p = 0; p < NP; ++p) { soff[p * 64 + tid] = zi; swt[p * 64 + tid] = zf; }
        } else {
            const size_t row = (size_t)b * LQ + qg;
            const float* oa = oaproj + row * 96;
            float4 l4 = *reinterpret_cast<const float4*>(oa + 64 + h * 4);
            float mx = fmaxf(fmaxf(l4.x, l4.y), fmaxf(l4.z, l4.w));
            float e0 = __expf(l4.x - mx), e1 = __expf(l4.y - mx);
            float e2 = __expf(l4.z - mx), e3 = __expf(l4.w - mx);
            float inv = 1.f / (e0 + e1 + e2 + e3);
            float ew[4] = {e0 * inv, e1 * inv, e2 * inv, e3 * inv};
            float4 o0 = *reinterpret_cast<const float4*>(oa + h * 8);
            float4 o1 = *reinterpret_cast<const float4*>(oa + h * 8 + 4);
            float oxv[4] = {o0.x, o0.z, o1.x, o1.z};
            float oyv[4] = {o0.y, o0.w, o1.y, o1.w};
            const float* rp = refpts + row * 4;
            float cx = rp[0], cy = rp[1], rw = rp[2], rh = rp[3];
            #pragma unroll
            for (int p = 0; p < NP; ++p) {
                float x = (cx + oxv[p] * rw * 0.125f) * (float)HWD - 0.5f;
                float y = (cy + oyv[p] * rh * 0.125f) * (float)HWD - 0.5f;
                float x0f = floorf(x), y0f = floorf(y);
                float wx = x - x0f, wy = y - y0f;
                int x0 = (int)x0f, y0 = (int)y0f;
                int x1 = x0 + 1, y1 = y0 + 1;
                float vx0 = (x0 >= 0 && x0 < HWD) ? 1.f : 0.f;
                float vx1 = (x1 >= 0 && x1 < HWD) ? 1.f : 0.f;
                float vy0 = (y0 >= 0 && y0 < HWD) ? 1.f : 0.f;
                float vy1 = (y1 >= 0 && y1 < HWD) ? 1.f : 0.f;
                int cx0 = min(max(x0, 0), HWD - 1), cx1 = min(max(x1, 0), HWD - 1);
                int cy0 = min(max(y0, 0), HWD - 1), cy1 = min(max(y1, 0), HWD - 1);
                float aw = ew[p];
                int4 of = {cy0 * HWD + cx0, cy0 * HWD + cx1,
                           cy1 * HWD + cx0, cy1 * HWD + cx1};
                float4 wt = {aw * (1.f - wx) * (1.f - wy) * vx0 * vy0,
                             aw * wx * (1.f - wy) * vx1 * vy0,
                             aw * (1.f - wx) * wy * vx0 * vy1,
                             aw * wx * wy * vx1 * vy1};
                soff[p * 64 + tid] = of;
                swt [p * 64 + tid] = wt;
            }
        }
    }
    __syncthreads();

    const int q = tid >> 2, c8 = tid & 3;
    const int qg = q0 + q;
    const ushort_t* vb = value + (size_t)map * (LIN * 32) + c8 * 8;

    int4 of[4]; float4 w4[4];
    #pragma unroll
    for (int p = 0; p < NP; ++p) {
        of[p] = soff[p * 64 + q];
        w4[p] = swt [p * 64 + q];
    }
    uint4 vv[4][4];
    #pragma unroll
    for (int p = 0; p < NP; ++p) {
        vv[p][0] = *reinterpret_cast<const uint4*>(vb + ((size_t)of[p].x << 5));
        vv[p][1] = *reinterpret_cast<const uint4*>(vb + ((size_t)of[p].y << 5));
        vv[p][2] = *reinterpret_cast<const uint4*>(vb + ((size_t)of[p].z << 5));
        vv[p][3] = *reinterpret_cast<const uint4*>(vb + ((size_t)of[p].w << 5));
    }
    float a0 = 0.f, a1 = 0.f, a2 = 0.f, a3 = 0.f;
    float a4 = 0.f, a5 = 0.f, a6 = 0.f, a7 = 0.f;
    #define ACC(V, W) { const float w_ = (W); const uint4 v_ = (V); \
        a0 += w_ * __uint_as_float(v_.x << 16); \
        a1 += w_ * __uint_as_float(v_.x & 0xffff0000u); \
        a2 += w_ * __uint_as_float(v_.y << 16); \
        a3 += w_ * __uint_as_float(v_.y & 0xffff0000u); \
        a4 += w_ * __uint_as_float(v_.z << 16); \
        a5 += w_ * __uint_as_float(v_.z & 0xffff0000u); \
        a6 += w_ * __uint_as_float(v_.w << 16); \
        a7 += w_ * __uint_as_float(v_.w & 0xffff0000u); }
    #pragma unroll
    for (int p = 0; p < NP; ++p) {
        ACC(vv[p][0], w4[p].x);
        ACC(vv[p][1], w4[p].y);
        ACC(vv[p][2], w4[p].z);
        ACC(vv[p][3], w4[p].w);
    }
    #undef ACC

    if (qg < LQ) {
        const size_t orow = (size_t)b * LQ + qg;
        u16x8 pk;
        pk[0] = f2bf(a0); pk[1] = f2bf(a1);
        pk[2] = f2bf(a2); pk[3] = f2bf(a3);
        pk[4] = f2bf(a4); pk[5] = f2bf(a5);
        pk[6] = f2bf(a6); pk[7] = f2bf(a7);
        // pre-swizzled store: chunk cc = h*4+c8 -> tile t = cc>>3,
        // storage ct = (cc&7) ^ ((orow>>1)&7)
        const int cc = h * 4 + c8;
        const int t = cc >> 3;
        const int ct = (cc & 7) ^ ((int)(orow >> 1) & 7);
        *reinterpret_cast<u16x8*>(&out[orow * 256 + t * 64 + ct * 8]) = pk;
    }
}

// ---------------------------------------------------------------------------
// Output GEMM: out = ws2 @ Wout + bout (f32). BM=64, BK=64, 4 waves.
// Both A (pre-swizzled ws2) and B (pre-swizzled WtO) staged via gload16.
// ---------------------------------------------------------------------------
__global__ __launch_bounds__(256) void gemm_out_kernel(
    const ushort_t* __restrict__ A, const ushort_t* __restrict__ Wt,
    const float* __restrict__ bias, float* __restrict__ Cout)
{
    __shared__ ushort_t As[64 * 64];
    __shared__ ushort_t Bs[256 * 64];

    const int tid  = threadIdx.x;
    const int lane = tid & 63;
    const int wv   = tid >> 6;
    const int row0 = blockIdx.x * 64;

    const f32x4 zero = {0.f, 0.f, 0.f, 0.f};
    f32x4 acc[4][4];
    #pragma unroll
    for (int m = 0; m < 4; ++m)
        #pragma unroll
        for (int n = 0; n < 4; ++n) acc[m][n] = zero;

    const int fr = lane & 15, kb = lane >> 4;
    const int ln8 = lane >> 3, lc8 = lane & 7;

    for (int k0 = 0; k0 < 256; k0 += 64) {
        const int t = k0 >> 6;
        #pragma unroll
        for (int it = 0; it < 2; ++it) {
            int r0 = (it * 4 + wv) * 8;
            gload16(&A[(size_t)(row0 + r0 + ln8) * 256 + t * 64 + lc8 * 8],
                    &As[r0 * 64]);
        }
        #pragma unroll
        for (int it = 0; it < 8; ++it) {
            int r0 = (it * 4 + wv) * 8;
            gload16(&Wt[(size_t)(r0 + ln8) * 256 + t * 64 + lc8 * 8],
                    &Bs[r0 * 64]);
        }
        __syncthreads();

        #pragma unroll
        for (int ks = 0; ks < 2; ++ks) {
            const int lc = ks * 4 + kb;
            bf16x8 af[4], bf[4];
            #pragma unroll
            for (int m = 0; m < 4; ++m) {
                int r = m * 16 + fr;
                af[m] = *reinterpret_cast<const bf16x8*>(
                    &As[r * 64 + ((lc ^ ((r >> 1) & 7)) * 8)]);
            }
            #pragma unroll
            for (int n = 0; n < 4; ++n) {
                int c = wv * 64 + n * 16 + fr;
                bf[n] = *reinterpret_cast<const bf16x8*>(
                    &Bs[c * 64 + ((lc ^ ((c >> 1) & 7)) * 8)]);
            }
            #pragma unroll
            for (int m = 0; m < 4; ++m)
                #pragma unroll
                for (int n = 0; n < 4; ++n)
                    acc[m][n] = __builtin_amdgcn_mfma_f32_16x16x32_bf16(
                        af[m], bf[n], acc[m][n], 0, 0, 0);
        }
        __syncthreads();
    }

    #pragma unroll
    for (int m = 0; m < 4; ++m) {
        #pragma unroll
        for (int n = 0; n < 4; ++n) {
            int c = wv * 64 + n * 16 + fr;
            float bb = bias[c];
            #pragma unroll
            for (int j = 0; j < 4; ++j) {
                int r = row0 + m * 16 + kb * 4 + j;
                Cout[(size_t)r * 256 + c] = acc[m][n][j] + bb;
            }
        }
    }
}

// ---------------------------------------------------------------------------
extern "C" void kernel_launch(void* const* d_in, const int* in_sizes, int n_in,
                              void* d_out, int out_size, void* d_ws, size_t ws_size,
                              hipStream_t stream)
{
    const float* query  = (const float*)d_in[0];
    const float* refpts = (const float*)d_in[1];
    const float* flat   = (const float*)d_in[2];
    const float* Wv   = (const float*)d_in[6];
    const float* bv   = (const float*)d_in[7];
    const float* Woff = (const float*)d_in[8];
    const float* boff = (const float*)d_in[9];
    const float* Wa   = (const float*)d_in[10];
    const float* ba   = (const float*)d_in[11];
    const float* Wout = (const float*)d_in[12];
    const float* bout = (const float*)d_in[13];
    float* out = (float*)d_out;

    const size_t MROWS = (size_t)BATCH * LIN;            // 40000
    ushort_t* value  = (ushort_t*)d_ws;                  // [b][h][pix][32] bf16
    ushort_t* ws2    = value + MROWS * DM;               // 40000x256 bf16 (pre-swizzled)
    ushort_t* WtV    = ws2 + MROWS * DM;                 // 256x256 bf16 (pre-swizzled)
    ushort_t* WtO    = WtV + 256 * 256;                  // 256x256 bf16 (pre-swizzled)
    ushort_t* Wcomb  = WtO + 256 * 256;                  // 96x256 bf16 (pre-swizzled)
    float*    bcomb  = (float*)(Wcomb + 96 * 256);       // 96 f32 (+pad)
    float*    oaproj = bcomb + 128;                      // 40000x96 f32

    dim3 blk(256);

    prep_kernel<<<dim3(256, 3), blk, 0, stream>>>(
        Wv, Wout, Woff, Wa, boff, ba, WtV, WtO, Wcomb, bcomb);

    gemm_in_kernel<<<dim3(1250), blk, 0, stream>>>(
        flat, query, WtV, Wcomb, bv, bcomb, value, oaproj);

    deform_kernel<<<dim3(157 * 32), blk, 0, stream>>>(
        oaproj, refpts, value, ws2);

    gemm_out_kernel<<<dim3(MROWS / 64), blk, 0, stream>>>(
        ws2, WtO, bout, out);
}

// Round 10
// 70.912 us; speedup vs baseline: 1.5392x; 1.0253x over previous
//
#include <hip/hip_runtime.h>

#define BATCH 4
#define LQ    10000
#define DM    256
#define NH    8
#define NP    4
#define HWD   100
#define LIN   10000

typedef unsigned short ushort_t;
typedef __attribute__((ext_vector_type(8))) short bf16x8;
typedef __attribute__((ext_vector_type(8))) unsigned short u16x8;
typedef __attribute__((ext_vector_type(4))) float f32x4;

__device__ __forceinline__ unsigned short f2bf(float f) {
    unsigned int u = __float_as_uint(f);
    u += 0x7FFFu + ((u >> 16) & 1u);          // round-to-nearest-even
    return (unsigned short)(u >> 16);
}

// async global->LDS, 16B per lane. LDS dest = wave-uniform base + lane*16.
__device__ __forceinline__ void gload16(const ushort_t* g, ushort_t* l) {
    __builtin_amdgcn_global_load_lds(
        (const __attribute__((address_space(1))) void*)g,
        (__attribute__((address_space(3))) void*)l, 16, 0, 0);
}

// Pre-swizzle (4-chunk, within each 32-k tile): storage chunk
// ct = lc ^ ((n>>1)&3). Frag ds_read_b128 then lands at the conflict-free
// floor (every bank hit exactly 8x per wave access). Staging is a LINEAR
// copy of the pre-swizzled storage -> gload16-compatible.
// ---------------------------------------------------------------------------
// Prep: swizzled WtV/WtO (256x256), Wcomb (96x256) + bcomb. grid (256,3).
// ---------------------------------------------------------------------------
__global__ __launch_bounds__(256) void prep_kernel(
    const float* __restrict__ Wv, const float* __restrict__ Wout,
    const float* __restrict__ Woff, const float* __restrict__ Wa,
    const float* __restrict__ boff, const float* __restrict__ ba,
    ushort_t* __restrict__ WtV, ushort_t* __restrict__ WtO,
    ushort_t* __restrict__ Wcomb, float* __restrict__ bcomb)
{
    const int n = blockIdx.x, k = threadIdx.x;
    const int t32 = k >> 5, lc = (k >> 3) & 3, j = k & 7;
    const int ct = lc ^ ((n >> 1) & 3);
    const size_t addr = (size_t)n * 256 + t32 * 32 + ct * 8 + j;
    if (blockIdx.y == 0) {
        WtV[addr] = f2bf(Wv[(size_t)k * 256 + n]);
    } else if (blockIdx.y == 1) {
        WtO[addr] = f2bf(Wout[(size_t)k * 256 + n]);
    } else if (n < 96) {
        float w = (n < 64) ? Woff[(size_t)k * 64 + n] : Wa[(size_t)k * 32 + (n - 64)];
        Wcomb[addr] = f2bf(w);
        if (k == 0) bcomb[n] = (n < 64) ? boff[n] : ba[n - 64];
    }
}

// ---------------------------------------------------------------------------
// Combined input GEMMs, 2-phase double-buffered (BM=64, BK=32, 4 waves):
//   bid <  625 : value_hm[((b*8+h)*LIN+pix)*32+ch] = bf16(flat @ Wv + bv)
//   bid >= 625 : oaproj[M][96] = f32(query @ [Woff|Wa]^T + bcomb)
// Per iter: issue A-reg loads + B gload16 for t+1 -> buf^1, compute buf,
// one __syncthreads. Staging latency hides under ds_read+MFMA.
// ---------------------------------------------------------------------------
__global__ __launch_bounds__(256) void gemm_in_kernel(
    const float* __restrict__ flat, const float* __restrict__ query,
    const ushort_t* __restrict__ WtV, const ushort_t* __restrict__ Wcomb,
    const float* __restrict__ bv, const float* __restrict__ bcomb,
    ushort_t* __restrict__ value, float* __restrict__ oaproj)
{
    __shared__ ushort_t As[2][64 * 32];     // 2 x 4 KB
    __shared__ ushort_t Bs[2][256 * 32];    // 2 x 16 KB

    const int tid  = threadIdx.x;
    const int lane = tid & 63;
    const int wv   = tid >> 6;

    const int ar  = tid >> 2;               // A staging row 0..63
    const int akb = tid & 3;                // A staging chunk 0..3
    const int asw = (akb ^ ((ar >> 1) & 3)) * 8;
    const int fr = lane & 15, kb = lane >> 4;
    const int ln4 = lane >> 2, lc4 = lane & 3;   // gload16 decomposition

    if (blockIdx.x < 625) {
        // ---------------- value GEMM ----------------
        const int row0 = blockIdx.x * 64;
        const float* ap = &flat[(size_t)(row0 + ar) * 256 + akb * 8];
        const f32x4 zero = {0.f, 0.f, 0.f, 0.f};
        f32x4 acc[4][4];
        #pragma unroll
        for (int m = 0; m < 4; ++m)
            #pragma unroll
            for (int n = 0; n < 4; ++n) acc[m][n] = zero;

        // prologue: stage tile 0 into buf 0
        {
            float4 f0 = *reinterpret_cast<const float4*>(ap);
            float4 f1 = *reinterpret_cast<const float4*>(ap + 4);
            u16x8 pk;
            pk[0] = f2bf(f0.x); pk[1] = f2bf(f0.y);
            pk[2] = f2bf(f0.z); pk[3] = f2bf(f0.w);
            pk[4] = f2bf(f1.x); pk[5] = f2bf(f1.y);
            pk[6] = f2bf(f1.z); pk[7] = f2bf(f1.w);
            *reinterpret_cast<u16x8*>(&As[0][ar * 32 + asw]) = pk;
            #pragma unroll
            for (int it = 0; it < 4; ++it) {
                int r0 = (it * 4 + wv) * 16;
                gload16(&WtV[(size_t)(r0 + ln4) * 256 + lc4 * 8], &Bs[0][r0 * 32]);
            }
        }
        __syncthreads();

        int c = 0;
        for (int t = 0; t < 8; ++t) {
            const int kn = (t + 1) * 32;
            const bool pf = (t < 7);
            float4 f0, f1;
            if (pf) {
                f0 = *reinterpret_cast<const float4*>(ap + kn);     // A first
                f1 = *reinterpret_cast<const float4*>(ap + kn + 4);
                #pragma unroll
                for (int it = 0; it < 4; ++it) {                    // then B
                    int r0 = (it * 4 + wv) * 16;
                    gload16(&WtV[(size_t)(r0 + ln4) * 256 + kn + lc4 * 8],
                            &Bs[c ^ 1][r0 * 32]);
                }
            }
            bf16x8 af[4], bf[4];
            #pragma unroll
            for (int m = 0; m < 4; ++m) {
                int r = m * 16 + fr;
                af[m] = *reinterpret_cast<const bf16x8*>(
                    &As[c][r * 32 + ((kb ^ ((r >> 1) & 3)) * 8)]);
            }
            #pragma unroll
            for (int n = 0; n < 4; ++n) {
                int cc = wv * 64 + n * 16 + fr;
                bf[n] = *reinterpret_cast<const bf16x8*>(
                    &Bs[c][cc * 32 + ((kb ^ ((cc >> 1) & 3)) * 8)]);
            }
            #pragma unroll
            for (int m = 0; m < 4; ++m)
                #pragma unroll
                for (int n = 0; n < 4; ++n)
                    acc[m][n] = __builtin_amdgcn_mfma_f32_16x16x32_bf16(
                        af[m], bf[n], acc[m][n], 0, 0, 0);
            if (pf) {
                u16x8 pk;
                pk[0] = f2bf(f0.x); pk[1] = f2bf(f0.y);
                pk[2] = f2bf(f0.z); pk[3] = f2bf(f0.w);
                pk[4] = f2bf(f1.x); pk[5] = f2bf(f1.y);
                pk[6] = f2bf(f1.z); pk[7] = f2bf(f1.w);
                *reinterpret_cast<u16x8*>(&As[c ^ 1][ar * 32 + asw]) = pk;
            }
            __syncthreads();
            c ^= 1;
        }

        // epilogue -> head-major value layout
        #pragma unroll
        for (int n = 0; n < 4; ++n) {
            int cc = wv * 64 + n * 16 + fr;
            float bb = bv[cc];
            int hh = cc >> 5, ch = cc & 31;
            #pragma unroll
            for (int m = 0; m < 4; ++m) {
                #pragma unroll
                for (int j = 0; j < 4; ++j) {
                    int r = row0 + m * 16 + kb * 4 + j;
                    int rb = (int)((unsigned)r / 10000u);
                    int pix = r - rb * 10000;
                    size_t addr = (((size_t)(rb * 8 + hh)) * LIN + pix) * 32 + ch;
                    value[addr] = f2bf(acc[m][n][j] + bb);
                }
            }
        }
    } else {
        // ---------------- projection GEMM ----------------
        const int row0 = (blockIdx.x - 625) * 64;
        const float* ap = &query[(size_t)(row0 + ar) * 256 + akb * 8];
        const f32x4 zero = {0.f, 0.f, 0.f, 0.f};
        f32x4 acc[6];
        #pragma unroll
        for (int n = 0; n < 6; ++n) acc[n] = zero;

        {
            float4 f0 = *reinterpret_cast<const float4*>(ap);
            float4 f1 = *reinterpret_cast<const float4*>(ap + 4);
            u16x8 pk;
            pk[0] = f2bf(f0.x); pk[1] = f2bf(f0.y);
            pk[2] = f2bf(f0.z); pk[3] = f2bf(f0.w);
            pk[4] = f2bf(f1.x); pk[5] = f2bf(f1.y);
            pk[6] = f2bf(f1.z); pk[7] = f2bf(f1.w);
            *reinterpret_cast<u16x8*>(&As[0][ar * 32 + asw]) = pk;
            #pragma unroll
            for (int it = 0; it < 2; ++it) {
                int r0 = (it * 4 + wv) * 16;
                if (r0 < 96)
                    gload16(&Wcomb[(size_t)(r0 + ln4) * 256 + lc4 * 8], &Bs[0][r0 * 32]);
            }
        }
        __syncthreads();

        int c = 0;
        for (int t = 0; t < 8; ++t) {
            const int kn = (t + 1) * 32;
            const bool pf = (t < 7);
            float4 f0, f1;
            if (pf) {
                f0 = *reinterpret_cast<const float4*>(ap + kn);
                f1 = *reinterpret_cast<const float4*>(ap + kn + 4);
                #pragma unroll
                for (int it = 0; it < 2; ++it) {
                    int r0 = (it * 4 + wv) * 16;
                    if (r0 < 96)
                        gload16(&Wcomb[(size_t)(r0 + ln4) * 256 + kn + lc4 * 8],
                                &Bs[c ^ 1][r0 * 32]);
                }
            }
            bf16x8 af;
            {
                int r = wv * 16 + fr;
                af = *reinterpret_cast<const bf16x8*>(
                    &As[c][r * 32 + ((kb ^ ((r >> 1) & 3)) * 8)]);
            }
            #pragma unroll
            for (int n = 0; n < 6; ++n) {
                int cc = n * 16 + fr;
                bf16x8 bf = *reinterpret_cast<const bf16x8*>(
                    &Bs[c][cc * 32 + ((kb ^ ((cc >> 1) & 3)) * 8)]);
                acc[n] = __builtin_amdgcn_mfma_f32_16x16x32_bf16(
                    af, bf, acc[n], 0, 0, 0);
            }
            if (pf) {
                u16x8 pk;
                pk[0] = f2bf(f0.x); pk[1] = f2bf(f0.y);
                pk[2] = f2bf(f0.z); pk[3] = f2bf(f0.w);
                pk[4] = f2bf(f1.x); pk[5] = f2bf(f1.y);
                pk[6] = f2bf(f1.z); pk[7] = f2bf(f1.w);
                *reinterpret_cast<u16x8*>(&As[c ^ 1][ar * 32 + asw]) = pk;
            }
            __syncthreads();
            c ^= 1;
        }

        #pragma unroll
        for (int n = 0; n < 6; ++n) {
            int cc = n * 16 + fr;
            float bb = bcomb[cc];
            #pragma unroll
            for (int j = 0; j < 4; ++j) {
                int r = row0 + wv * 16 + kb * 4 + j;
                oaproj[(size_t)r * 96 + cc] = acc[n][j] + bb;
            }
        }
    }
}

// ---------------------------------------------------------------------------
// Deform (R8/R9 structure, L2-resident per-map gather). ws2 store uses the
// 4-chunk pre-swizzle so gemm_out can stage it with gload16.
// ---------------------------------------------------------------------------
__global__ __launch_bounds__(256, 4) void deform_kernel(
    const float* __restrict__ oaproj, const float* __restrict__ refpts,
    const ushort_t* __restrict__ value, ushort_t* __restrict__ out)
{
    __shared__ int4   soff[NP * 64];
    __shared__ float4 swt [NP * 64];

    const int blk = blockIdx.x;
    const int xcd = blk & 7;
    const int sub = (blk >> 3) & 3;
    const int chunk = blk >> 5;
    const int map = xcd * 4 + sub;
    const int b = map >> 3, h = map & 7;
    const int q0 = chunk * 64;

    const int tid = threadIdx.x;

    if (tid < 64) {
        const int qg = q0 + tid;
        if (qg >= LQ) {
            int4 zi = {0, 0, 0, 0};
            float4 zf = {0.f, 0.f, 0.f, 0.f};
            #pragma unroll
            for (int p = 0; p < NP; ++p) { soff[p * 64 + tid] = zi; swt[p * 64 + tid] = zf; }
        } else {
            const size_t row = (size_t)b * LQ + qg;
            const float* oa = oaproj + row * 96;
            float4 l4 = *reinterpret_cast<const float4*>(oa + 64 + h * 4);
            float mx = fmaxf(fmaxf(l4.x, l4.y), fmaxf(l4.z, l4.w));
            float e0 = __expf(l4.x - mx), e1 = __expf(l4.y - mx);
            float e2 = __expf(l4.z - mx), e3 = __expf(l4.w - mx);
            float inv = 1.f / (e0 + e1 + e2 + e3);
            float ew[4] = {e0 * inv, e1 * inv, e2 * inv, e3 * inv};
            float4 o0 = *reinterpret_cast<const float4*>(oa + h * 8);
            float4 o1 = *reinterpret_cast<const float4*>(oa + h * 8 + 4);
            float oxv[4] = {o0.x, o0.z, o1.x, o1.z};
            float oyv[4] = {o0.y, o0.w, o1.y, o1.w};
            const float* rp = refpts + row * 4;
            float cx = rp[0], cy = rp[1], rw = rp[2], rh = rp[3];
            #pragma unroll
            for (int p = 0; p < NP; ++p) {
                float x = (cx + oxv[p] * rw * 0.125f) * (float)HWD - 0.5f;
                float y = (cy + oyv[p] * rh * 0.125f) * (float)HWD - 0.5f;
                float x0f = floorf(x), y0f = floorf(y);
                float wx = x - x0f, wy = y - y0f;
                int x0 = (int)x0f, y0 = (int)y0f;
                int x1 = x0 + 1, y1 = y0 + 1;
                float vx0 = (x0 >= 0 && x0 < HWD) ? 1.f : 0.f;
                float vx1 = (x1 >= 0 && x1 < HWD) ? 1.f : 0.f;
                float vy0 = (y0 >= 0 && y0 < HWD) ? 1.f : 0.f;
                float vy1 = (y1 >= 0 && y1 < HWD) ? 1.f : 0.f;
                int cx0 = min(max(x0, 0), HWD - 1), cx1 = min(max(x1, 0), HWD - 1);
                int cy0 = min(max(y0, 0), HWD - 1), cy1 = min(max(y1, 0), HWD - 1);
                float aw = ew[p];
                int4 of = {cy0 * HWD + cx0, cy0 * HWD + cx1,
                           cy1 * HWD + cx0, cy1 * HWD + cx1};
                float4 wt = {aw * (1.f - wx) * (1.f - wy) * vx0 * vy0,
                             aw * wx * (1.f - wy) * vx1 * vy0,
                             aw * (1.f - wx) * wy * vx0 * vy1,
                             aw * wx * wy * vx1 * vy1};
                soff[p * 64 + tid] = of;
                swt [p * 64 + tid] = wt;
            }
        }
    }
    __syncthreads();

    const int q = tid >> 2, c8 = tid & 3;
    const int qg = q0 + q;
    const ushort_t* vb = value + (size_t)map * (LIN * 32) + c8 * 8;

    int4 of[4]; float4 w4[4];
    #pragma unroll
    for (int p = 0; p < NP; ++p) {
        of[p] = soff[p * 64 + q];
        w4[p] = swt [p * 64 + q];
    }
    uint4 vv[4][4];
    #pragma unroll
    for (int p = 0; p < NP; ++p) {
        vv[p][0] = *reinterpret_cast<const uint4*>(vb + ((size_t)of[p].x << 5));
        vv[p][1] = *reinterpret_cast<const uint4*>(vb + ((size_t)of[p].y << 5));
        vv[p][2] = *reinterpret_cast<const uint4*>(vb + ((size_t)of[p].z << 5));
        vv[p][3] = *reinterpret_cast<const uint4*>(vb + ((size_t)of[p].w << 5));
    }
    float a0 = 0.f, a1 = 0.f, a2 = 0.f, a3 = 0.f;
    float a4 = 0.f, a5 = 0.f, a6 = 0.f, a7 = 0.f;
    #define ACC(V, W) { const float w_ = (W); const uint4 v_ = (V); \
        a0 += w_ * __uint_as_float(v_.x << 16); \
        a1 += w_ * __uint_as_float(v_.x & 0xffff0000u); \
        a2 += w_ * __uint_as_float(v_.y << 16); \
        a3 += w_ * __uint_as_float(v_.y & 0xffff0000u); \
        a4 += w_ * __uint_as_float(v_.z << 16); \
        a5 += w_ * __uint_as_float(v_.z & 0xffff0000u); \
        a6 += w_ * __uint_as_float(v_.w << 16); \
        a7 += w_ * __uint_as_float(v_.w & 0xffff0000u); }
    #pragma unroll
    for (int p = 0; p < NP; ++p) {
        ACC(vv[p][0], w4[p].x);
        ACC(vv[p][1], w4[p].y);
        ACC(vv[p][2], w4[p].z);
        ACC(vv[p][3], w4[p].w);
    }
    #undef ACC

    if (qg < LQ) {
        const size_t orow = (size_t)b * LQ + qg;
        u16x8 pk;
        pk[0] = f2bf(a0); pk[1] = f2bf(a1);
        pk[2] = f2bf(a2); pk[3] = f2bf(a3);
        pk[4] = f2bf(a4); pk[5] = f2bf(a5);
        pk[6] = f2bf(a6); pk[7] = f2bf(a7);
        // 4-chunk pre-swizzled store: cc = h*4+c8 -> tile t32 = cc>>2,
        // storage ct = (cc&3) ^ ((orow>>1)&3)
        const int cc = h * 4 + c8;
        const int t32 = cc >> 2;
        const int ct = (cc & 3) ^ ((int)(orow >> 1) & 3);
        *reinterpret_cast<u16x8*>(&out[orow * 256 + t32 * 32 + ct * 8]) = pk;
    }
}

// ---------------------------------------------------------------------------
// Output GEMM: out = ws2 @ Wout + bout (f32). BM=64, BK=32, 2-phase dbuf,
// both A (pre-swizzled ws2) and B (pre-swizzled WtO) staged via gload16.
// ---------------------------------------------------------------------------
__global__ __launch_bounds__(256) void gemm_out_kernel(
    const ushort_t* __restrict__ A, const ushort_t* __restrict__ Wt,
    const float* __restrict__ bias, float* __restrict__ Cout)
{
    __shared__ ushort_t As[2][64 * 32];
    __shared__ ushort_t Bs[2][256 * 32];

    const int tid  = threadIdx.x;
    const int lane = tid & 63;
    const int wv   = tid >> 6;
    const int row0 = blockIdx.x * 64;

    const f32x4 zero = {0.f, 0.f, 0.f, 0.f};
    f32x4 acc[4][4];
    #pragma unroll
    for (int m = 0; m < 4; ++m)
        #pragma unroll
        for (int n = 0; n < 4; ++n) acc[m][n] = zero;

    const int fr = lane & 15, kb = lane >> 4;
    const int ln4 = lane >> 2, lc4 = lane & 3;

    // prologue: stage tile 0
    {
        gload16(&A[(size_t)(row0 + wv * 16 + ln4) * 256 + lc4 * 8],
                &As[0][wv * 512]);
        #pragma unroll
        for (int it = 0; it < 4; ++it) {
            int r0 = (it * 4 + wv) * 16;
            gload16(&Wt[(size_t)(r0 + ln4) * 256 + lc4 * 8], &Bs[0][r0 * 32]);
        }
    }
    __syncthreads();

    int c = 0;
    for (int t = 0; t < 8; ++t) {
        const int kn = (t + 1) * 32;
        if (t < 7) {
            gload16(&A[(size_t)(row0 + wv * 16 + ln4) * 256 + kn + lc4 * 8],
                    &As[c ^ 1][wv * 512]);
            #pragma unroll
            for (int it = 0; it < 4; ++it) {
                int r0 = (it * 4 + wv) * 16;
                gload16(&Wt[(size_t)(r0 + ln4) * 256 + kn + lc4 * 8],
                        &Bs[c ^ 1][r0 * 32]);
            }
        }
        bf16x8 af[4], bf[4];
        #pragma unroll
        for (int m = 0; m < 4; ++m) {
            int r = m * 16 + fr;
            af[m] = *reinterpret_cast<const bf16x8*>(
                &As[c][r * 32 + ((kb ^ ((r >> 1) & 3)) * 8)]);
        }
        #pragma unroll
        for (int n = 0; n < 4; ++n) {
            int cc = wv * 64 + n * 16 + fr;
            bf[n] = *reinterpret_cast<const bf16x8*>(
                &Bs[c][cc * 32 + ((kb ^ ((cc >> 1) & 3)) * 8)]);
        }
        #pragma unroll
        for (int m = 0; m < 4; ++m)
            #pragma unroll
            for (int n = 0; n < 4; ++n)
                acc[m][n] = __builtin_amdgcn_mfma_f32_16x16x32_bf16(
                    af[m], bf[n], acc[m][n], 0, 0, 0);
        __syncthreads();
        c ^= 1;
    }

    #pragma unroll
    for (int m = 0; m < 4; ++m) {
        #pragma unroll
        for (int n = 0; n < 4; ++n) {
            int cc = wv * 64 + n * 16 + fr;
            float bb = bias[cc];
            #pragma unroll
            for (int j = 0; j < 4; ++j) {
                int r = row0 + m * 16 + kb * 4 + j;
                Cout[(size_t)r * 256 + cc] = acc[m][n][j] + bb;
            }
        }
    }
}

// ---------------------------------------------------------------------------
extern "C" void kernel_launch(void* const* d_in, const int* in_sizes, int n_in,
                              void* d_out, int out_size, void* d_ws, size_t ws_size,
                              hipStream_t stream)
{
    const float* query  = (const float*)d_in[0];
    const float* refpts = (const float*)d_in[1];
    const float* flat   = (const float*)d_in[2];
    const float* Wv   = (const float*)d_in[6];
    const float* bv   = (const float*)d_in[7];
    const float* Woff = (const float*)d_in[8];
    const float* boff = (const float*)d_in[9];
    const float* Wa   = (const float*)d_in[10];
    const float* ba   = (const float*)d_in[11];
    const float* Wout = (const float*)d_in[12];
    const float* bout = (const float*)d_in[13];
    float* out = (float*)d_out;

    const size_t MROWS = (size_t)BATCH * LIN;            // 40000
    ushort_t* value  = (ushort_t*)d_ws;                  // [b][h][pix][32] bf16
    ushort_t* ws2    = value + MROWS * DM;               // 40000x256 bf16 (pre-swizzled)
    ushort_t* WtV    = ws2 + MROWS * DM;                 // 256x256 bf16 (pre-swizzled)
    ushort_t* WtO    = WtV + 256 * 256;                  // 256x256 bf16 (pre-swizzled)
    ushort_t* Wcomb  = WtO + 256 * 256;                  // 96x256 bf16 (pre-swizzled)
    float*    bcomb  = (float*)(Wcomb + 96 * 256);       // 96 f32 (+pad)
    float*    oaproj = bcomb + 128;                      // 40000x96 f32

    dim3 blk(256);

    prep_kernel<<<dim3(256, 3), blk, 0, stream>>>(
        Wv, Wout, Woff, Wa, boff, ba, WtV, WtO, Wcomb, bcomb);

    gemm_in_kernel<<<dim3(1250), blk, 0, stream>>>(
        flat, query, WtV, Wcomb, bv, bcomb, value, oaproj);

    deform_kernel<<<dim3(157 * 32), blk, 0, stream>>>(
        oaproj, refpts, value, ws2);

    gemm_out_kernel<<<dim3(MROWS / 64), blk, 0, stream>>>(
        ws2, WtO, bout, out);
}